// Round 1
// baseline (1906.031 us; speedup 1.0000x reference)
//
#include <hip/hip_runtime.h>

// DictLearn: W column-normalize -> power method (100 it) -> IHT sparse coding
// (50 it, K=64 hard threshold) -> X = W @ Gamma.
// Outputs in d_out: X [512*1024] fp32, Gamma [1024*1024] fp32, norms [50] fp32.
//
// Key design decisions:
//  * Power method runs in Z = X@Wn^T space on S = Wn Wn^T (512x512); steps use
//    S2 = S*S/64 (exact pow2 scaling, /8 per single step) -> 51 launches, no
//    per-step normalization rounding. c = 8*||v100||/||v99||.
//  * X0 reproduces jax.random.normal(key(42),(1,1024)) bit-exactly:
//    threefry2x32 keys (0,42), counters (i, i+512), + XLA's Giles erfinv_f32.
//  * IHT uses Gamma 64-sparsity: residual@W = Gamma@Q - YW with Q = Wn^T Wn,
//    ||R||^2 = <Gamma Q, Gamma> - 2<Gamma, YW> + ||Y||^2 (double accumulate).
//  * Hard threshold = exact 65th-largest |value| via 4-pass radix select on
//    float bit patterns; keep strictly greater (matches jnp semantics + ties).

#define DEV __device__ __forceinline__

constexpr int Nd = 512;    // signal dim
constexpr int Md = 1024;   // atoms
constexpr int Bd = 1024;   // batch
constexpr int Ksp = 64;    // sparsity K
constexpr int IHT = 50;

DEV float wave_reduce_f(float v) {
#pragma unroll
  for (int off = 32; off > 0; off >>= 1) v += __shfl_down(v, off);
  return v;
}
DEV double wave_reduce_d(double v) {
#pragma unroll
  for (int off = 32; off > 0; off >>= 1) v += __shfl_down(v, off);
  return v;
}

__global__ void k_zero(double* dacc) {
  int t = threadIdx.x;
  if (t < 51) dacc[t] = 0.0;  // [0]=Yn2, [1..50]=norm accumulators
}

__global__ __launch_bounds__(256) void k_colnorm(const float* __restrict__ W,
                                                 float* __restrict__ cnorm) {
  int col = blockIdx.x * 256 + threadIdx.x;  // 1024 cols
  double ss = 0.0;
  for (int i = 0; i < Nd; ++i) {
    float w = W[(size_t)i * Md + col];
    ss = fma((double)w, (double)w, ss);
  }
  cnorm[col] = (float)sqrt(ss);
}

__global__ __launch_bounds__(256) void k_normalize(const float* __restrict__ W,
                                                   const float* __restrict__ cnorm,
                                                   float* __restrict__ Wn) {
  int idx = blockIdx.x * 256 + threadIdx.x;  // 512*1024
  Wn[idx] = W[idx] / cnorm[idx & (Md - 1)];
}

__global__ __launch_bounds__(256) void k_yn2(const float* __restrict__ Y,
                                             double* __restrict__ dacc) {
  double s = 0.0;
  for (int i = blockIdx.x * 256 + threadIdx.x; i < Bd * Nd; i += gridDim.x * 256) {
    float y = Y[i];
    s = fma((double)y, (double)y, s);
  }
  s = wave_reduce_d(s);
  __shared__ double red[4];
  int lane = threadIdx.x & 63, wid = threadIdx.x >> 6;
  if (lane == 0) red[wid] = s;
  __syncthreads();
  if (threadIdx.x == 0) atomicAdd(&dacc[0], red[0] + red[1] + red[2] + red[3]);
}

// C[m,n] = scale * sum_k A(m,k)*B(k,n); ta/tb: operand stored transposed.
// 32x32 tiles, 256 threads, 2x2 per thread. K-sequential (deterministic).
__global__ __launch_bounds__(256) void k_gemm(const float* __restrict__ A, int lda, int ta,
                                              const float* __restrict__ B, int ldb, int tb,
                                              float* __restrict__ C, int ldc, int Kd,
                                              float scale) {
  __shared__ float As[32][33];
  __shared__ float Bs[32][33];
  const int tid = threadIdx.x;
  const int tx = tid & 15, ty = tid >> 4;
  const int m0 = blockIdx.y * 32, n0 = blockIdx.x * 32;
  float a00 = 0.f, a01 = 0.f, a10 = 0.f, a11 = 0.f;
  for (int k0 = 0; k0 < Kd; k0 += 32) {
#pragma unroll
    for (int e = 0; e < 4; ++e) {
      const int idx = tid + e * 256;
      if (!ta) { const int r = idx >> 5, c = idx & 31; As[r][c] = A[(size_t)(m0 + r) * lda + (k0 + c)]; }
      else     { const int r = idx & 31, c = idx >> 5; As[r][c] = A[(size_t)(k0 + c) * lda + (m0 + r)]; }
      if (!tb) { const int r = idx >> 5, c = idx & 31; Bs[r][c] = B[(size_t)(k0 + r) * ldb + (n0 + c)]; }
      else     { const int r = idx & 31, c = idx >> 5; Bs[r][c] = B[(size_t)(n0 + c) * ldb + (k0 + r)]; }
    }
    __syncthreads();
#pragma unroll 8
    for (int kk = 0; kk < 32; ++kk) {
      const float av0 = As[ty * 2][kk], av1 = As[ty * 2 + 1][kk];
      const float bv0 = Bs[kk][tx * 2], bv1 = Bs[kk][tx * 2 + 1];
      a00 = fmaf(av0, bv0, a00); a01 = fmaf(av0, bv1, a01);
      a10 = fmaf(av1, bv0, a10); a11 = fmaf(av1, bv1, a11);
    }
    __syncthreads();
  }
  C[(size_t)(m0 + ty * 2) * ldc + (n0 + tx * 2)]         = a00 * scale;
  C[(size_t)(m0 + ty * 2) * ldc + (n0 + tx * 2 + 1)]     = a01 * scale;
  C[(size_t)(m0 + ty * 2 + 1) * ldc + (n0 + tx * 2)]     = a10 * scale;
  C[(size_t)(m0 + ty * 2 + 1) * ldc + (n0 + tx * 2 + 1)] = a11 * scale;
}

// XLA ErfInvF32 (Giles) — matches jax/XLA erf_inv on f32.
DEV float erfinv_xla(float x) {
  float w = -log1pf(-x * x);
  float p;
  if (w < 5.0f) {
    w = w - 2.5f;
    p = 2.81022636e-08f;
    p = fmaf(p, w, 3.43273939e-07f);
    p = fmaf(p, w, -3.5233877e-06f);
    p = fmaf(p, w, -4.39150654e-06f);
    p = fmaf(p, w, 0.00021858087f);
    p = fmaf(p, w, -0.00125372503f);
    p = fmaf(p, w, -0.00417768164f);
    p = fmaf(p, w, 0.246640727f);
    p = fmaf(p, w, 1.50140941f);
  } else {
    w = sqrtf(w) - 3.0f;
    p = -0.000200214257f;
    p = fmaf(p, w, 0.000100950558f);
    p = fmaf(p, w, 0.00134934322f);
    p = fmaf(p, w, -0.00367342844f);
    p = fmaf(p, w, 0.00573950773f);
    p = fmaf(p, w, -0.0076224613f);
    p = fmaf(p, w, 0.00943887047f);
    p = fmaf(p, w, 1.00167406f);
    p = fmaf(p, w, 2.83297682f);
  }
  return p * x;
}

#define TF_ROUND(r)                                  \
  {                                                  \
    x0 += x1;                                        \
    x1 = (x1 << (r)) | (x1 >> (32 - (r)));           \
    x1 ^= x0;                                        \
  }

// X0 = jax.random.normal(jax.random.key(42), (1,1024), f32), bit-exact bits.
__global__ void k_x0(float* __restrict__ X0) {
  unsigned i = threadIdx.x;  // 0..511; counter pair (i, i+512)
  unsigned x0 = i, x1 = i + 512u;
  const unsigned ks0 = 0u, ks1 = 42u, ks2 = 0x1BD11BDAu ^ 42u;
  x0 += ks0; x1 += ks1;
  TF_ROUND(13) TF_ROUND(15) TF_ROUND(26) TF_ROUND(6)  x0 += ks1; x1 += ks2 + 1u;
  TF_ROUND(17) TF_ROUND(29) TF_ROUND(16) TF_ROUND(24) x0 += ks2; x1 += ks0 + 2u;
  TF_ROUND(13) TF_ROUND(15) TF_ROUND(26) TF_ROUND(6)  x0 += ks0; x1 += ks1 + 3u;
  TF_ROUND(17) TF_ROUND(29) TF_ROUND(16) TF_ROUND(24) x0 += ks1; x1 += ks2 + 4u;
  TF_ROUND(13) TF_ROUND(15) TF_ROUND(26) TF_ROUND(6)  x0 += ks2; x1 += ks0 + 5u;
  const float lo = -0.99999994f;      // nextafter(-1, 0) in f32
  const float sqrt2 = 1.41421356237f; // rounds to 0x3FB504F3
  {
    float f = __uint_as_float((x0 >> 9) | 0x3f800000u) - 1.0f;
    float u = fmaxf(lo, f * 2.0f + lo);  // (hi-lo) == 2.0f exactly in f32
    X0[i] = sqrt2 * erfinv_xla(u);
  }
  {
    float f = __uint_as_float((x1 >> 9) | 0x3f800000u) - 1.0f;
    float u = fmaxf(lo, f * 2.0f + lo);
    X0[i + 512] = sqrt2 * erfinv_xla(u);
  }
}

// z0 = X0 @ Wn^T  (512 outputs, dot length 1024). One wave per row.
__global__ __launch_bounds__(256) void k_z0(const float* __restrict__ X0,
                                            const float* __restrict__ Wn,
                                            float* __restrict__ vout) {
  const int lane = threadIdx.x & 63, wid = threadIdx.x >> 6;
  const int row = blockIdx.x * 4 + wid;  // < 512
  const float4* wr = (const float4*)(Wn + (size_t)row * Md);
  const float4* x4 = (const float4*)X0;
  float s = 0.f;
#pragma unroll
  for (int e = 0; e < 4; ++e) {
    const float4 w4 = wr[lane + e * 64];
    const float4 xx = x4[lane + e * 64];
    s = fmaf(w4.x, xx.x, s); s = fmaf(w4.y, xx.y, s);
    s = fmaf(w4.z, xx.z, s); s = fmaf(w4.w, xx.w, s);
  }
  s = wave_reduce_f(s);
  if (lane == 0) vout[row] = s;
}

// vout = (vin @ Msym) * scale ; Msym is 512x512 symmetric. One wave per row.
__global__ __launch_bounds__(256) void k_pmv(const float* __restrict__ Mmat,
                                             const float* __restrict__ vin,
                                             float* __restrict__ vout, float scale) {
  const int lane = threadIdx.x & 63, wid = threadIdx.x >> 6;
  const int row = blockIdx.x * 4 + wid;  // < 512
  const float4* mr = (const float4*)(Mmat + (size_t)row * Nd);
  const float4* v4 = (const float4*)vin;
  float s = 0.f;
#pragma unroll
  for (int e = 0; e < 2; ++e) {
    const float4 m4 = mr[lane + e * 64];
    const float4 xx = v4[lane + e * 64];
    s = fmaf(m4.x, xx.x, s); s = fmaf(m4.y, xx.y, s);
    s = fmaf(m4.z, xx.z, s); s = fmaf(m4.w, xx.w, s);
  }
  s = wave_reduce_f(s);
  if (lane == 0) vout[row] = s * scale;
}

__global__ __launch_bounds__(512) void k_pfinal(const float* __restrict__ v99,
                                                const float* __restrict__ v100,
                                                float* __restrict__ cbuf) {
  __shared__ double r99[8], r100[8];
  const int t = threadIdx.x, lane = t & 63, wid = t >> 6;
  double a = (double)v99[t]; a *= a;
  double b = (double)v100[t]; b *= b;
  a = wave_reduce_d(a);
  b = wave_reduce_d(b);
  if (lane == 0) { r99[wid] = a; r100[wid] = b; }
  __syncthreads();
  if (t == 0) {
    double n99 = 0.0, n100 = 0.0;
    for (int i = 0; i < 8; ++i) { n99 += r99[i]; n100 += r100[i]; }
    float c = (float)(8.0 * sqrt(n100 / n99));  // last pre-norm ||X2||
    cbuf[0] = c;
    cbuf[1] = 1.0f / c;  // eta
  }
}

// Fused IHT iteration: one workgroup per batch row.
// it == -1 : U = eta*YW row (init),                 -> sparse out
// it >= 0  : P = Gamma@Q (sparse), norm term (it>=1), U = Gamma - eta*(P-YW),
//            radix-select 65th largest |U|, strict >, ordered compaction.
// it == IHT-1 additionally writes the dense Gamma row to d_out.
__global__ __launch_bounds__(256) void k_select(
    int it, const float* __restrict__ Q, const float* __restrict__ YW,
    const float* __restrict__ cbuf,
    const int* __restrict__ in_idx, const float* __restrict__ in_val,
    const int* __restrict__ in_cnt,
    int* __restrict__ out_idx, float* __restrict__ out_val, int* __restrict__ out_cnt,
    float* __restrict__ gdense, double* __restrict__ normacc) {
  __shared__ float u[Md];
  __shared__ float sval[Ksp];
  __shared__ int sidx[Ksp];
  __shared__ unsigned hist[256];
  __shared__ unsigned scanb[256];
  __shared__ unsigned sel_need, sel_prefix;
  __shared__ double dred[4];

  const int t = threadIdx.x;
  const int b = blockIdx.x;
  const int lane = t & 63, wid = t >> 6;
  const float eta = cbuf[1];

  if (it >= 0) {
    const int cnt = in_cnt[b];
    if (t < cnt) { sidx[t] = in_idx[b * Ksp + t]; sval[t] = in_val[b * Ksp + t]; }
    __syncthreads();
    float4 p = make_float4(0.f, 0.f, 0.f, 0.f);
    for (int k = 0; k < cnt; ++k) {
      const int id = sidx[k];
      const float g = sval[k];
      const float4 q = ((const float4*)(Q + (size_t)id * Md))[t];
      p.x = fmaf(g, q.x, p.x); p.y = fmaf(g, q.y, p.y);
      p.z = fmaf(g, q.z, p.z); p.w = fmaf(g, q.w, p.w);
    }
    ((float4*)u)[t] = p;  // u holds P for the norm dot
    __syncthreads();
    if (it >= 1) {
      double part = 0.0;
      if (t < cnt) {
        const int id = sidx[t];
        part = (double)sval[t] * ((double)u[id] - 2.0 * (double)YW[(size_t)b * Md + id]);
      }
      part = wave_reduce_d(part);
      if (lane == 0) dred[wid] = part;
      __syncthreads();
      if (t == 0) atomicAdd(&normacc[it - 1], dred[0] + dred[1] + dred[2] + dred[3]);
      __syncthreads();
    }
    const float4 yw = ((const float4*)(YW + (size_t)b * Md))[t];
    float4 uu;
    uu.x = -(eta * (p.x - yw.x)); uu.y = -(eta * (p.y - yw.y));
    uu.z = -(eta * (p.z - yw.z)); uu.w = -(eta * (p.w - yw.w));
    ((float4*)u)[t] = uu;
    __syncthreads();
    if (t < cnt) u[sidx[t]] += sval[t];  // distinct indices, no race
    __syncthreads();
  } else {
    const float4 yw = ((const float4*)(YW + (size_t)b * Md))[t];
    float4 uu;
    uu.x = eta * yw.x; uu.y = eta * yw.y; uu.z = eta * yw.z; uu.w = eta * yw.w;
    ((float4*)u)[t] = uu;
    __syncthreads();
  }

  // ---- radix select: exact bit pattern of the (K+1)-th largest |u| ----
  unsigned need = Ksp + 1, prefix = 0u, pmask = 0u;
  for (int pass = 3; pass >= 0; --pass) {
    const int sh = 8 * pass;
    hist[t] = 0u;
    __syncthreads();
#pragma unroll
    for (int e = 0; e < 4; ++e) {
      const unsigned key = __float_as_uint(u[t * 4 + e]) & 0x7fffffffu;
      if ((key & pmask) == prefix) atomicAdd(&hist[(key >> sh) & 255u], 1u);
    }
    __syncthreads();
    scanb[t] = hist[t];
    __syncthreads();
    for (int off = 1; off < 256; off <<= 1) {  // inclusive suffix sums
      const unsigned cur = scanb[t];
      const unsigned add = (t + off < 256) ? scanb[t + off] : 0u;
      __syncthreads();
      scanb[t] = cur + add;
      __syncthreads();
    }
    const unsigned incl = scanb[t];
    const unsigned excl = (t < 255) ? scanb[t + 1] : 0u;
    if (incl >= need && excl < need) {
      sel_prefix = prefix | ((unsigned)t << sh);
      sel_need = need - excl;
    }
    __syncthreads();
    prefix = sel_prefix;
    need = sel_need;
    pmask |= (255u << sh);
    __syncthreads();
  }
  const unsigned Tbits = prefix;

  // ---- ordered compaction (deterministic, ascending column order) ----
  unsigned keep = 0u;
  int myc = 0;
  float vals[4];
#pragma unroll
  for (int e = 0; e < 4; ++e) {
    vals[e] = u[t * 4 + e];
    const unsigned key = __float_as_uint(vals[e]) & 0x7fffffffu;
    if (key > Tbits) { keep |= (1u << e); ++myc; }
  }
  scanb[t] = (unsigned)myc;
  __syncthreads();
  for (int off = 1; off < 256; off <<= 1) {  // inclusive prefix sums
    const unsigned cur = scanb[t];
    const unsigned add = (t >= off) ? scanb[t - off] : 0u;
    __syncthreads();
    scanb[t] = cur + add;
    __syncthreads();
  }
  int base = (int)scanb[t] - myc;
#pragma unroll
  for (int e = 0; e < 4; ++e) {
    if (keep & (1u << e)) {
      out_idx[b * Ksp + base] = t * 4 + e;
      out_val[b * Ksp + base] = vals[e];
      ++base;
    }
  }
  if (t == 0) out_cnt[b] = (int)scanb[255];
  if (it == IHT - 1) {
    float4 g;
    g.x = (keep & 1u) ? vals[0] : 0.f;
    g.y = (keep & 2u) ? vals[1] : 0.f;
    g.z = (keep & 4u) ? vals[2] : 0.f;
    g.w = (keep & 8u) ? vals[3] : 0.f;
    ((float4*)(gdense + (size_t)b * Md))[t] = g;
  }
}

// Final residual-norm term for Gamma_50 (norms[49]).
__global__ __launch_bounds__(64) void k_norm50(const int* __restrict__ in_idx,
                                               const float* __restrict__ in_val,
                                               const int* __restrict__ in_cnt,
                                               const float* __restrict__ Q,
                                               const float* __restrict__ YW,
                                               double* __restrict__ normacc) {
  __shared__ int sidx[Ksp];
  __shared__ float sval[Ksp];
  const int t = threadIdx.x, b = blockIdx.x;
  const int cnt = in_cnt[b];
  if (t < cnt) { sidx[t] = in_idx[b * Ksp + t]; sval[t] = in_val[b * Ksp + t]; }
  __syncthreads();
  double part = 0.0;
  if (t < cnt) {
    const int id = sidx[t];
    float acc = 0.f;
    for (int k = 0; k < cnt; ++k) acc = fmaf(sval[k], Q[(size_t)sidx[k] * Md + id], acc);
    part = (double)sval[t] * ((double)acc - 2.0 * (double)YW[(size_t)b * Md + id]);
  }
  part = wave_reduce_d(part);
  if (t == 0) atomicAdd(&normacc[IHT - 1], part);
}

__global__ void k_wnorms(const double* __restrict__ dacc, float* __restrict__ onorms) {
  const int t = threadIdx.x;
  if (t < IHT) {
    const double yn2 = dacc[0];
    double r2 = yn2 + dacc[1 + t];
    if (r2 < 0.0) r2 = 0.0;
    onorms[t] = (float)(sqrt(r2) / sqrt(yn2));
  }
}

extern "C" void kernel_launch(void* const* d_in, const int* in_sizes, int n_in,
                              void* d_out, int out_size, void* d_ws, size_t ws_size,
                              hipStream_t stream) {
  (void)in_sizes; (void)n_in; (void)out_size; (void)ws_size;  // K hardcoded = 64
  const float* Y = (const float*)d_in[0];  // [1024,512]
  const float* W = (const float*)d_in[1];  // [512,1024]
  float* out = (float*)d_out;
  float* outX = out;                   // [512,1024]
  float* outG = out + Nd * Md;         // [1024,1024]
  float* outN = outG + Bd * Md;        // [50]

  // workspace layout (~13.4 MB)
  char* wsb = (char*)d_ws;
  double* dacc = (double*)wsb;               // 51 doubles
  float* cbuf = (float*)(wsb + 512);         // [0]=c, [1]=eta
  float* Wn = (float*)(wsb + 1024);          // 512*1024
  float* Q = Wn + Nd * Md;                   // 1024*1024
  float* YW = Q + Md * Md;                   // 1024*1024
  float* Smat = YW + Bd * Md;                // 512*512
  float* S2 = Smat + Nd * Nd;                // 512*512
  float* cnorm = S2 + Nd * Nd;               // 1024
  float* X0 = cnorm + Md;                    // 1024
  float* V = X0 + Md;                        // 4*512 power-iter slots
  float* valA = V + 2048;                    // 1024*64
  float* valB = valA + Bd * Ksp;             // 1024*64
  int* idxA = (int*)(valB + Bd * Ksp);       // 1024*64
  int* idxB = idxA + Bd * Ksp;               // 1024*64
  int* cntA = idxB + Bd * Ksp;               // 1024
  int* cntB = cntA + Bd;                     // 1024

  k_zero<<<1, 64, 0, stream>>>(dacc);
  k_colnorm<<<4, 256, 0, stream>>>(W, cnorm);
  k_normalize<<<2048, 256, 0, stream>>>(W, cnorm, Wn);

  // S = Wn Wn^T (512x512, K=1024); S2 = S*S/64; Q = Wn^T Wn (K=512); YW = Y Wn
  k_gemm<<<dim3(16, 16), 256, 0, stream>>>(Wn, Md, 0, Wn, Md, 1, Smat, Nd, Md, 1.0f);
  k_gemm<<<dim3(16, 16), 256, 0, stream>>>(Smat, Nd, 0, Smat, Nd, 0, S2, Nd, Nd, 0.015625f);
  k_gemm<<<dim3(32, 32), 256, 0, stream>>>(Wn, Md, 1, Wn, Md, 0, Q, Md, Nd, 1.0f);
  k_gemm<<<dim3(32, 32), 256, 0, stream>>>(Y, Nd, 0, Wn, Md, 0, YW, Md, Nd, 1.0f);
  k_yn2<<<128, 256, 0, stream>>>(Y, dacc);

  // power method in Z-space: z0 = X0 @ Wn^T; 49 steps of S2, 2 steps of S/8
  k_x0<<<1, 512, 0, stream>>>(X0);
  k_z0<<<128, 256, 0, stream>>>(X0, Wn, V);
  float* pin = V;
  float* pout = V + 512;
  for (int i = 0; i < 49; ++i) {
    k_pmv<<<128, 256, 0, stream>>>(S2, pin, pout, 1.0f);
    float* tp = pin; pin = pout; pout = tp;
  }
  k_pmv<<<128, 256, 0, stream>>>(Smat, pin, V + 1024, 0.125f);        // v99
  k_pmv<<<128, 256, 0, stream>>>(Smat, V + 1024, V + 1536, 0.125f);   // v100
  k_pfinal<<<1, 512, 0, stream>>>(V + 1024, V + 1536, cbuf);

  // IHT: init threshold of eta*YW, then 50 fused iterations (ping-pong A/B)
  k_select<<<1024, 256, 0, stream>>>(-1, Q, YW, cbuf, (const int*)nullptr,
                                     (const float*)nullptr, (const int*)nullptr,
                                     idxA, valA, cntA, outG, dacc + 1);
  for (int it = 0; it < IHT; ++it) {
    const bool even = (it & 1) == 0;
    k_select<<<1024, 256, 0, stream>>>(it, Q, YW, cbuf,
                                       even ? idxA : idxB, even ? valA : valB,
                                       even ? cntA : cntB,
                                       even ? idxB : idxA, even ? valB : valA,
                                       even ? cntB : cntA, outG, dacc + 1);
  }
  k_norm50<<<1024, 64, 0, stream>>>(idxA, valA, cntA, Q, YW, dacc + 1);  // Gamma_50 in A
  k_wnorms<<<1, 64, 0, stream>>>(dacc, outN);

  // X = Wn @ Gamma (512x1024, K=1024) reading dense Gamma from d_out
  k_gemm<<<dim3(32, 16), 256, 0, stream>>>(Wn, Md, 0, outG, Md, 0, outX, Md, Md, 1.0f);
}

// Round 3
// 1851.099 us; speedup vs baseline: 1.0297x; 1.0297x over previous
//
#include <hip/hip_runtime.h>

// DictLearn: W column-normalize -> power method (100 it) -> IHT sparse coding
// (50 it, K=64 hard threshold) -> X = W @ Gamma.
// Outputs in d_out: X [512*1024] fp32, Gamma [1024*1024] fp32, norms [50] fp32.
//
// R3 = R2 with the X-path bug fixed: R2's k_xsparse computed Wn @ Gamma^T
// (row-sparse gather hits X columns, not rows). X is back to the dense
// k_gemm64 (correct R1 formulation, now on the fast 64x64 GEMM).
// Trajectory (eta, IHT supports, Gamma, norms) is bit-identical to R1.

#define DEV __device__ __forceinline__

constexpr int Nd = 512;    // signal dim
constexpr int Md = 1024;   // atoms
constexpr int Bd = 1024;   // batch
constexpr int Ksp = 64;    // sparsity K
constexpr int IHT = 50;

DEV float wave_reduce_f(float v) {
#pragma unroll
  for (int off = 32; off > 0; off >>= 1) v += __shfl_down(v, off);
  return v;
}
DEV double wave_reduce_d(double v) {
#pragma unroll
  for (int off = 32; off > 0; off >>= 1) v += __shfl_down(v, off);
  return v;
}

__global__ void k_zero(double* dacc) {
  int t = threadIdx.x;
  if (t < 51) dacc[t] = 0.0;  // [0]=Yn2, [1..50]=norm accumulators
}

__global__ __launch_bounds__(256) void k_colnorm(const float* __restrict__ W,
                                                 float* __restrict__ cnorm) {
  int col = blockIdx.x * 256 + threadIdx.x;  // 1024 cols
  double ss = 0.0;
  for (int i = 0; i < Nd; ++i) {
    float w = W[(size_t)i * Md + col];
    ss = fma((double)w, (double)w, ss);
  }
  cnorm[col] = (float)sqrt(ss);
}

__global__ __launch_bounds__(256) void k_normalize(const float* __restrict__ W,
                                                   const float* __restrict__ cnorm,
                                                   float* __restrict__ Wn) {
  int idx = blockIdx.x * 256 + threadIdx.x;  // 512*1024
  Wn[idx] = W[idx] / cnorm[idx & (Md - 1)];
}

__global__ __launch_bounds__(256) void k_yn2(const float* __restrict__ Y,
                                             double* __restrict__ dacc) {
  double s = 0.0;
  for (int i = blockIdx.x * 256 + threadIdx.x; i < Bd * Nd; i += gridDim.x * 256) {
    float y = Y[i];
    s = fma((double)y, (double)y, s);
  }
  s = wave_reduce_d(s);
  __shared__ double red[4];
  int lane = threadIdx.x & 63, wid = threadIdx.x >> 6;
  if (lane == 0) red[wid] = s;
  __syncthreads();
  if (threadIdx.x == 0) atomicAdd(&dacc[0], red[0] + red[1] + red[2] + red[3]);
}

// C[m,n] = scale * sum_k A(m,k)*B(k,n); ta/tb: operand stored transposed.
// 64x64 tiles, 256 threads, 4x4 per thread, BK=32. K-sequential per element
// (bit-identical accumulation order to the R1 32x32 kernel).
__global__ __launch_bounds__(256) void k_gemm64(const float* __restrict__ A, int lda, int ta,
                                                const float* __restrict__ B, int ldb, int tb,
                                                float* __restrict__ C, int ldc, int Kd,
                                                float scale) {
  __shared__ __align__(16) float As[32][68];  // [kk][m], pad 68 -> 272B rows (16B aligned)
  __shared__ __align__(16) float Bs[32][68];  // [kk][n]
  const int tid = threadIdx.x;
  const int tx = tid & 15, ty = tid >> 4;
  const int m0 = blockIdx.y * 64, n0 = blockIdx.x * 64;
  float acc[4][4];
#pragma unroll
  for (int i = 0; i < 4; ++i)
#pragma unroll
    for (int j = 0; j < 4; ++j) acc[i][j] = 0.f;

  for (int k0 = 0; k0 < Kd; k0 += 32) {
    if (!ta) {
      const int c = tid & 31, r0 = tid >> 5;  // 8 rows/pass
#pragma unroll
      for (int i = 0; i < 8; ++i) {
        const int r = r0 + i * 8;
        As[c][r] = A[(size_t)(m0 + r) * lda + (k0 + c)];
      }
    } else {
      const int r = tid & 63, c0 = tid >> 6;  // 4 cols/pass
#pragma unroll
      for (int i = 0; i < 8; ++i) {
        const int c = c0 + i * 4;
        As[c][r] = A[(size_t)(k0 + c) * lda + (m0 + r)];
      }
    }
    if (!tb) {
      const int c = tid & 63, r0 = tid >> 6;
#pragma unroll
      for (int i = 0; i < 8; ++i) {
        const int r = r0 + i * 4;
        Bs[r][c] = B[(size_t)(k0 + r) * ldb + (n0 + c)];
      }
    } else {
      const int r = tid & 31, c0 = tid >> 5;
#pragma unroll
      for (int i = 0; i < 8; ++i) {
        const int c = c0 + i * 8;
        Bs[r][c] = B[(size_t)(n0 + c) * ldb + (k0 + r)];
      }
    }
    __syncthreads();
#pragma unroll
    for (int kk = 0; kk < 32; ++kk) {
      const float4 a4 = *(const float4*)&As[kk][ty * 4];
      const float4 b4 = *(const float4*)&Bs[kk][tx * 4];
      acc[0][0] = fmaf(a4.x, b4.x, acc[0][0]);
      acc[0][1] = fmaf(a4.x, b4.y, acc[0][1]);
      acc[0][2] = fmaf(a4.x, b4.z, acc[0][2]);
      acc[0][3] = fmaf(a4.x, b4.w, acc[0][3]);
      acc[1][0] = fmaf(a4.y, b4.x, acc[1][0]);
      acc[1][1] = fmaf(a4.y, b4.y, acc[1][1]);
      acc[1][2] = fmaf(a4.y, b4.z, acc[1][2]);
      acc[1][3] = fmaf(a4.y, b4.w, acc[1][3]);
      acc[2][0] = fmaf(a4.z, b4.x, acc[2][0]);
      acc[2][1] = fmaf(a4.z, b4.y, acc[2][1]);
      acc[2][2] = fmaf(a4.z, b4.z, acc[2][2]);
      acc[2][3] = fmaf(a4.z, b4.w, acc[2][3]);
      acc[3][0] = fmaf(a4.w, b4.x, acc[3][0]);
      acc[3][1] = fmaf(a4.w, b4.y, acc[3][1]);
      acc[3][2] = fmaf(a4.w, b4.z, acc[3][2]);
      acc[3][3] = fmaf(a4.w, b4.w, acc[3][3]);
    }
    __syncthreads();
  }
#pragma unroll
  for (int i = 0; i < 4; ++i) {
    float4 o;
    o.x = acc[i][0] * scale;
    o.y = acc[i][1] * scale;
    o.z = acc[i][2] * scale;
    o.w = acc[i][3] * scale;
    *(float4*)&C[(size_t)(m0 + ty * 4 + i) * ldc + n0 + tx * 4] = o;
  }
}

// XLA ErfInvF32 (Giles) — matches jax/XLA erf_inv on f32.
DEV float erfinv_xla(float x) {
  float w = -log1pf(-x * x);
  float p;
  if (w < 5.0f) {
    w = w - 2.5f;
    p = 2.81022636e-08f;
    p = fmaf(p, w, 3.43273939e-07f);
    p = fmaf(p, w, -3.5233877e-06f);
    p = fmaf(p, w, -4.39150654e-06f);
    p = fmaf(p, w, 0.00021858087f);
    p = fmaf(p, w, -0.00125372503f);
    p = fmaf(p, w, -0.00417768164f);
    p = fmaf(p, w, 0.246640727f);
    p = fmaf(p, w, 1.50140941f);
  } else {
    w = sqrtf(w) - 3.0f;
    p = -0.000200214257f;
    p = fmaf(p, w, 0.000100950558f);
    p = fmaf(p, w, 0.00134934322f);
    p = fmaf(p, w, -0.00367342844f);
    p = fmaf(p, w, 0.00573950773f);
    p = fmaf(p, w, -0.0076224613f);
    p = fmaf(p, w, 0.00943887047f);
    p = fmaf(p, w, 1.00167406f);
    p = fmaf(p, w, 2.83297682f);
  }
  return p * x;
}

#define TF_ROUND(r)                                  \
  {                                                  \
    x0 += x1;                                        \
    x1 = (x1 << (r)) | (x1 >> (32 - (r)));           \
    x1 ^= x0;                                        \
  }

// X0 = jax.random.normal(jax.random.key(42), (1,1024), f32), bit-exact bits.
__global__ void k_x0(float* __restrict__ X0) {
  unsigned i = threadIdx.x;  // 0..511; counter pair (i, i+512)
  unsigned x0 = i, x1 = i + 512u;
  const unsigned ks0 = 0u, ks1 = 42u, ks2 = 0x1BD11BDAu ^ 42u;
  x0 += ks0; x1 += ks1;
  TF_ROUND(13) TF_ROUND(15) TF_ROUND(26) TF_ROUND(6)  x0 += ks1; x1 += ks2 + 1u;
  TF_ROUND(17) TF_ROUND(29) TF_ROUND(16) TF_ROUND(24) x0 += ks2; x1 += ks0 + 2u;
  TF_ROUND(13) TF_ROUND(15) TF_ROUND(26) TF_ROUND(6)  x0 += ks0; x1 += ks1 + 3u;
  TF_ROUND(17) TF_ROUND(29) TF_ROUND(16) TF_ROUND(24) x0 += ks1; x1 += ks2 + 4u;
  TF_ROUND(13) TF_ROUND(15) TF_ROUND(26) TF_ROUND(6)  x0 += ks2; x1 += ks0 + 5u;
  const float lo = -0.99999994f;      // nextafter(-1, 0) in f32
  const float sqrt2 = 1.41421356237f; // rounds to 0x3FB504F3
  {
    float f = __uint_as_float((x0 >> 9) | 0x3f800000u) - 1.0f;
    float u = fmaxf(lo, f * 2.0f + lo);  // (hi-lo) == 2.0f exactly in f32
    X0[i] = sqrt2 * erfinv_xla(u);
  }
  {
    float f = __uint_as_float((x1 >> 9) | 0x3f800000u) - 1.0f;
    float u = fmaxf(lo, f * 2.0f + lo);
    X0[i + 512] = sqrt2 * erfinv_xla(u);
  }
}

// z0 = X0 @ Wn^T  (512 outputs, dot length 1024). One wave per row.
__global__ __launch_bounds__(256) void k_z0(const float* __restrict__ X0,
                                            const float* __restrict__ Wn,
                                            float* __restrict__ vout) {
  const int lane = threadIdx.x & 63, wid = threadIdx.x >> 6;
  const int row = blockIdx.x * 4 + wid;  // < 512
  const float4* wr = (const float4*)(Wn + (size_t)row * Md);
  const float4* x4 = (const float4*)X0;
  float s = 0.f;
#pragma unroll
  for (int e = 0; e < 4; ++e) {
    const float4 w4 = wr[lane + e * 64];
    const float4 xx = x4[lane + e * 64];
    s = fmaf(w4.x, xx.x, s); s = fmaf(w4.y, xx.y, s);
    s = fmaf(w4.z, xx.z, s); s = fmaf(w4.w, xx.w, s);
  }
  s = wave_reduce_f(s);
  if (lane == 0) vout[row] = s;
}

// vout = (vin @ Msym) * scale ; Msym is 512x512 symmetric. One wave per row.
__global__ __launch_bounds__(256) void k_pmv(const float* __restrict__ Mmat,
                                             const float* __restrict__ vin,
                                             float* __restrict__ vout, float scale) {
  const int lane = threadIdx.x & 63, wid = threadIdx.x >> 6;
  const int row = blockIdx.x * 4 + wid;  // < 512
  const float4* mr = (const float4*)(Mmat + (size_t)row * Nd);
  const float4* v4 = (const float4*)vin;
  float s = 0.f;
#pragma unroll
  for (int e = 0; e < 2; ++e) {
    const float4 m4 = mr[lane + e * 64];
    const float4 xx = v4[lane + e * 64];
    s = fmaf(m4.x, xx.x, s); s = fmaf(m4.y, xx.y, s);
    s = fmaf(m4.z, xx.z, s); s = fmaf(m4.w, xx.w, s);
  }
  s = wave_reduce_f(s);
  if (lane == 0) vout[row] = s * scale;
}

__global__ __launch_bounds__(512) void k_pfinal(const float* __restrict__ v99,
                                                const float* __restrict__ v100,
                                                float* __restrict__ cbuf) {
  __shared__ double r99[8], r100[8];
  const int t = threadIdx.x, lane = t & 63, wid = t >> 6;
  double a = (double)v99[t]; a *= a;
  double b = (double)v100[t]; b *= b;
  a = wave_reduce_d(a);
  b = wave_reduce_d(b);
  if (lane == 0) { r99[wid] = a; r100[wid] = b; }
  __syncthreads();
  if (t == 0) {
    double n99 = 0.0, n100 = 0.0;
    for (int i = 0; i < 8; ++i) { n99 += r99[i]; n100 += r100[i]; }
    float c = (float)(8.0 * sqrt(n100 / n99));  // last pre-norm ||X2||
    cbuf[0] = c;
    cbuf[1] = 1.0f / c;  // eta
  }
}

// Fused IHT iteration: one workgroup per batch row.
// it == -1 : U = eta*YW row (init),                 -> sparse out
// it >= 0  : P = Gamma@Q (sparse), norm term (it>=1), U = Gamma - eta*(P-YW),
//            radix-select 65th largest |U|, strict >, ordered compaction.
// it == IHT-1 additionally writes the dense Gamma row to d_out.
__global__ __launch_bounds__(256) void k_select(
    int it, const float* __restrict__ Q, const float* __restrict__ YW,
    const float* __restrict__ cbuf,
    const int* __restrict__ in_idx, const float* __restrict__ in_val,
    const int* __restrict__ in_cnt,
    int* __restrict__ out_idx, float* __restrict__ out_val, int* __restrict__ out_cnt,
    float* __restrict__ gdense, double* __restrict__ normacc) {
  __shared__ float u[Md];
  __shared__ float sval[Ksp];
  __shared__ int sidx[Ksp];
  __shared__ unsigned hist[256];
  __shared__ unsigned wred[4];
  __shared__ unsigned sel_need, sel_prefix;
  __shared__ double dred[4];

  const int t = threadIdx.x;
  const int b = blockIdx.x;
  const int lane = t & 63, wv = t >> 6;
  const float eta = cbuf[1];

  if (it >= 0) {
    const int cnt = in_cnt[b];
    if (t < cnt) { sidx[t] = in_idx[b * Ksp + t]; sval[t] = in_val[b * Ksp + t]; }
    __syncthreads();
    const float4* Q4 = (const float4*)Q;
    float4 p = make_float4(0.f, 0.f, 0.f, 0.f);
    int k = 0;
    for (; k + 4 <= cnt; k += 4) {  // 4 loads in flight; fma order is k-ascending
      const int i0 = sidx[k], i1 = sidx[k + 1], i2 = sidx[k + 2], i3 = sidx[k + 3];
      const float g0 = sval[k], g1 = sval[k + 1], g2 = sval[k + 2], g3 = sval[k + 3];
      const float4 q0 = Q4[(size_t)i0 * 256 + t];
      const float4 q1 = Q4[(size_t)i1 * 256 + t];
      const float4 q2 = Q4[(size_t)i2 * 256 + t];
      const float4 q3 = Q4[(size_t)i3 * 256 + t];
      p.x = fmaf(g0, q0.x, p.x); p.x = fmaf(g1, q1.x, p.x);
      p.x = fmaf(g2, q2.x, p.x); p.x = fmaf(g3, q3.x, p.x);
      p.y = fmaf(g0, q0.y, p.y); p.y = fmaf(g1, q1.y, p.y);
      p.y = fmaf(g2, q2.y, p.y); p.y = fmaf(g3, q3.y, p.y);
      p.z = fmaf(g0, q0.z, p.z); p.z = fmaf(g1, q1.z, p.z);
      p.z = fmaf(g2, q2.z, p.z); p.z = fmaf(g3, q3.z, p.z);
      p.w = fmaf(g0, q0.w, p.w); p.w = fmaf(g1, q1.w, p.w);
      p.w = fmaf(g2, q2.w, p.w); p.w = fmaf(g3, q3.w, p.w);
    }
    for (; k < cnt; ++k) {
      const int id = sidx[k];
      const float g = sval[k];
      const float4 q = Q4[(size_t)id * 256 + t];
      p.x = fmaf(g, q.x, p.x); p.y = fmaf(g, q.y, p.y);
      p.z = fmaf(g, q.z, p.z); p.w = fmaf(g, q.w, p.w);
    }
    ((float4*)u)[t] = p;  // u holds P for the norm dot
    __syncthreads();
    if (it >= 1) {
      double part = 0.0;
      if (t < cnt) {
        const int id = sidx[t];
        part = (double)sval[t] * ((double)u[id] - 2.0 * (double)YW[(size_t)b * Md + id]);
      }
      part = wave_reduce_d(part);
      if (lane == 0) dred[wv] = part;
      __syncthreads();
      if (t == 0) atomicAdd(&normacc[it - 1], dred[0] + dred[1] + dred[2] + dred[3]);
      __syncthreads();
    }
    const float4 yw = ((const float4*)(YW + (size_t)b * Md))[t];
    float4 uu;
    uu.x = -(eta * (p.x - yw.x)); uu.y = -(eta * (p.y - yw.y));
    uu.z = -(eta * (p.z - yw.z)); uu.w = -(eta * (p.w - yw.w));
    ((float4*)u)[t] = uu;
    __syncthreads();
    if (t < cnt) u[sidx[t]] += sval[t];  // distinct indices, no race
    __syncthreads();
  } else {
    const float4 yw = ((const float4*)(YW + (size_t)b * Md))[t];
    float4 uu;
    uu.x = eta * yw.x; uu.y = eta * yw.y; uu.z = eta * yw.z; uu.w = eta * yw.w;
    ((float4*)u)[t] = uu;
    __syncthreads();
  }

  // keys/vals in registers for all passes + compaction
  float vals[4];
  unsigned key[4];
  {
    const float4 mv = ((const float4*)u)[t];
    vals[0] = mv.x; vals[1] = mv.y; vals[2] = mv.z; vals[3] = mv.w;
#pragma unroll
    for (int e = 0; e < 4; ++e) key[e] = __float_as_uint(vals[e]) & 0x7fffffffu;
  }

  // ---- radix select: exact bit pattern of the (K+1)-th largest |u| ----
  unsigned need = Ksp + 1, prefix = 0u, pmask = 0u;
  for (int pass = 3; pass >= 0; --pass) {
    const int sh = 8 * pass;
    hist[t] = 0u;
    __syncthreads();
#pragma unroll
    for (int e = 0; e < 4; ++e)
      if ((key[e] & pmask) == prefix) atomicAdd(&hist[(key[e] >> sh) & 255u], 1u);
    __syncthreads();
    const unsigned h = hist[t];
    unsigned x = h;
#pragma unroll
    for (int off = 1; off < 64; off <<= 1) {  // wave-level inclusive suffix scan
      const unsigned y = __shfl_down(x, off);
      if (lane + off < 64) x += y;
    }
    if (lane == 0) wred[wv] = x;  // wave total
    __syncthreads();
    unsigned addhi = 0u;
    for (int w2 = wv + 1; w2 < 4; ++w2) addhi += wred[w2];
    const unsigned incl = x + addhi;      // count of keys with bin >= t
    const unsigned excl = incl - h;       // count of keys with bin >  t
    if (incl >= need && excl < need) {
      sel_prefix = prefix | ((unsigned)t << sh);
      sel_need = need - excl;
    }
    __syncthreads();
    prefix = sel_prefix;
    need = sel_need;
    pmask |= (255u << sh);
  }
  const unsigned Tbits = prefix;

  // ---- ordered compaction (deterministic, ascending column order) ----
  unsigned keep = 0u;
  unsigned myc = 0u;
#pragma unroll
  for (int e = 0; e < 4; ++e)
    if (key[e] > Tbits) { keep |= (1u << e); ++myc; }
  unsigned x = myc;
#pragma unroll
  for (int off = 1; off < 64; off <<= 1) {  // wave-level inclusive prefix scan
    const unsigned y = __shfl_up(x, off);
    if (lane >= off) x += y;
  }
  __syncthreads();               // wred reuse: prior reads complete
  if (lane == 63) wred[wv] = x;  // wave total
  __syncthreads();
  unsigned addlo = 0u;
  for (int w2 = 0; w2 < wv; ++w2) addlo += wred[w2];
  int base = (int)(x + addlo) - (int)myc;  // exclusive prefix in thread order
#pragma unroll
  for (int e = 0; e < 4; ++e) {
    if (keep & (1u << e)) {
      out_idx[b * Ksp + base] = t * 4 + e;
      out_val[b * Ksp + base] = vals[e];
      ++base;
    }
  }
  if (t == 0) out_cnt[b] = (int)(wred[0] + wred[1] + wred[2] + wred[3]);
  if (it == IHT - 1) {
    float4 g;
    g.x = (keep & 1u) ? vals[0] : 0.f;
    g.y = (keep & 2u) ? vals[1] : 0.f;
    g.z = (keep & 4u) ? vals[2] : 0.f;
    g.w = (keep & 8u) ? vals[3] : 0.f;
    ((float4*)(gdense + (size_t)b * Md))[t] = g;
  }
}

// Final residual-norm term for Gamma_50 (norms[49]).
__global__ __launch_bounds__(64) void k_norm50(const int* __restrict__ in_idx,
                                               const float* __restrict__ in_val,
                                               const int* __restrict__ in_cnt,
                                               const float* __restrict__ Q,
                                               const float* __restrict__ YW,
                                               double* __restrict__ normacc) {
  __shared__ int sidx[Ksp];
  __shared__ float sval[Ksp];
  const int t = threadIdx.x, b = blockIdx.x;
  const int cnt = in_cnt[b];
  if (t < cnt) { sidx[t] = in_idx[b * Ksp + t]; sval[t] = in_val[b * Ksp + t]; }
  __syncthreads();
  double part = 0.0;
  if (t < cnt) {
    const int id = sidx[t];
    float acc = 0.f;
    for (int k = 0; k < cnt; ++k) acc = fmaf(sval[k], Q[(size_t)sidx[k] * Md + id], acc);
    part = (double)sval[t] * ((double)acc - 2.0 * (double)YW[(size_t)b * Md + id]);
  }
  part = wave_reduce_d(part);
  if (t == 0) atomicAdd(&normacc[IHT - 1], part);
}

__global__ void k_wnorms(const double* __restrict__ dacc, float* __restrict__ onorms) {
  const int t = threadIdx.x;
  if (t < IHT) {
    const double yn2 = dacc[0];
    double r2 = yn2 + dacc[1 + t];
    if (r2 < 0.0) r2 = 0.0;
    onorms[t] = (float)(sqrt(r2) / sqrt(yn2));
  }
}

extern "C" void kernel_launch(void* const* d_in, const int* in_sizes, int n_in,
                              void* d_out, int out_size, void* d_ws, size_t ws_size,
                              hipStream_t stream) {
  (void)in_sizes; (void)n_in; (void)out_size; (void)ws_size;  // K hardcoded = 64
  const float* Y = (const float*)d_in[0];  // [1024,512]
  const float* W = (const float*)d_in[1];  // [512,1024]
  float* out = (float*)d_out;
  float* outX = out;                   // [512,1024]
  float* outG = out + Nd * Md;         // [1024,1024]
  float* outN = outG + Bd * Md;        // [50]

  // workspace layout (~13.4 MB)
  char* wsb = (char*)d_ws;
  double* dacc = (double*)wsb;               // 51 doubles
  float* cbuf = (float*)(wsb + 512);         // [0]=c, [1]=eta
  float* Wn = (float*)(wsb + 1024);          // 512*1024
  float* Q = Wn + Nd * Md;                   // 1024*1024
  float* YW = Q + Md * Md;                   // 1024*1024
  float* Smat = YW + Bd * Md;                // 512*512
  float* S2 = Smat + Nd * Nd;                // 512*512
  float* cnorm = S2 + Nd * Nd;               // 1024
  float* X0 = cnorm + Md;                    // 1024
  float* V = X0 + Md;                        // 4*512 power-iter slots
  float* valA = V + 2048;                    // 1024*64
  float* valB = valA + Bd * Ksp;             // 1024*64
  int* idxA = (int*)(valB + Bd * Ksp);       // 1024*64
  int* idxB = idxA + Bd * Ksp;               // 1024*64
  int* cntA = idxB + Bd * Ksp;               // 1024
  int* cntB = cntA + Bd;                     // 1024

  k_zero<<<1, 64, 0, stream>>>(dacc);
  k_colnorm<<<4, 256, 0, stream>>>(W, cnorm);
  k_normalize<<<2048, 256, 0, stream>>>(W, cnorm, Wn);

  // S = Wn Wn^T (512x512, K=1024); S2 = S*S/64; Q = Wn^T Wn (K=512); YW = Y Wn
  k_gemm64<<<dim3(8, 8), 256, 0, stream>>>(Wn, Md, 0, Wn, Md, 1, Smat, Nd, Md, 1.0f);
  k_gemm64<<<dim3(8, 8), 256, 0, stream>>>(Smat, Nd, 0, Smat, Nd, 0, S2, Nd, Nd, 0.015625f);
  k_gemm64<<<dim3(16, 16), 256, 0, stream>>>(Wn, Md, 1, Wn, Md, 0, Q, Md, Nd, 1.0f);
  k_gemm64<<<dim3(16, 16), 256, 0, stream>>>(Y, Nd, 0, Wn, Md, 0, YW, Md, Nd, 1.0f);
  k_yn2<<<128, 256, 0, stream>>>(Y, dacc);

  // power method in Z-space: z0 = X0 @ Wn^T; 49 steps of S2, 2 steps of S/8
  k_x0<<<1, 512, 0, stream>>>(X0);
  k_z0<<<128, 256, 0, stream>>>(X0, Wn, V);
  float* pin = V;
  float* pout = V + 512;
  for (int i = 0; i < 49; ++i) {
    k_pmv<<<128, 256, 0, stream>>>(S2, pin, pout, 1.0f);
    float* tp = pin; pin = pout; pout = tp;
  }
  k_pmv<<<128, 256, 0, stream>>>(Smat, pin, V + 1024, 0.125f);        // v99
  k_pmv<<<128, 256, 0, stream>>>(Smat, V + 1024, V + 1536, 0.125f);   // v100
  k_pfinal<<<1, 512, 0, stream>>>(V + 1024, V + 1536, cbuf);

  // IHT: init threshold of eta*YW, then 50 fused iterations (ping-pong A/B)
  k_select<<<1024, 256, 0, stream>>>(-1, Q, YW, cbuf, (const int*)nullptr,
                                     (const float*)nullptr, (const int*)nullptr,
                                     idxA, valA, cntA, outG, dacc + 1);
  for (int it = 0; it < IHT; ++it) {
    const bool even = (it & 1) == 0;
    k_select<<<1024, 256, 0, stream>>>(it, Q, YW, cbuf,
                                       even ? idxA : idxB, even ? valA : valB,
                                       even ? cntA : cntB,
                                       even ? idxB : idxA, even ? valB : valA,
                                       even ? cntB : cntA, outG, dacc + 1);
  }
  k_norm50<<<1024, 64, 0, stream>>>(idxA, valA, cntA, Q, YW, dacc + 1);  // Gamma_50 in A
  k_wnorms<<<1, 64, 0, stream>>>(dacc, outN);

  // X = Wn @ Gamma (512x1024, K=1024) reading dense Gamma from d_out
  k_gemm64<<<dim3(16, 8), 256, 0, stream>>>(Wn, Md, 0, outG, Md, 0, outX, Md, Md, 1.0f);
}

// Round 4
// 1093.062 us; speedup vs baseline: 1.7438x; 1.6935x over previous
//
#include <hip/hip_runtime.h>

// DictLearn: W column-normalize -> power method (100 it) -> IHT sparse coding
// (50 it, K=64 hard threshold) -> X = W @ Gamma.
// Outputs in d_out: X [512*1024] fp32, Gamma [1024*1024] fp32, norms [50] fp32.
//
// R4 changes vs R3 (trajectory bit-identical: per-element fmaf chains and eta
// unchanged):
//  * k_iht_all: ALL 51 IHT iterations in one launch (rows are independent;
//    norms via device atomics). Sparse state + YW row live in LDS/regs.
//  * k_gemm_t<BM,BN,TN>: register double-buffered staging; 64x32 tiles for
//    small-grid GEMMs (Smat/S2/X) so grid >= 128 blocks, 64x64 for Q/YW.
//  * Power chain (51 k_pmv) deliberately untouched: eta bits must not move.

#define DEV __device__ __forceinline__

constexpr int Nd = 512;    // signal dim
constexpr int Md = 1024;   // atoms
constexpr int Bd = 1024;   // batch
constexpr int Ksp = 64;    // sparsity K
constexpr int IHT = 50;

DEV float wave_reduce_f(float v) {
#pragma unroll
  for (int off = 32; off > 0; off >>= 1) v += __shfl_down(v, off);
  return v;
}
DEV double wave_reduce_d(double v) {
#pragma unroll
  for (int off = 32; off > 0; off >>= 1) v += __shfl_down(v, off);
  return v;
}

__global__ void k_zero(double* dacc) {
  int t = threadIdx.x;
  if (t < 51) dacc[t] = 0.0;  // [0]=Yn2, [1..50]=norm accumulators
}

__global__ __launch_bounds__(256) void k_colnorm(const float* __restrict__ W,
                                                 float* __restrict__ cnorm) {
  int col = blockIdx.x * 256 + threadIdx.x;  // 1024 cols
  double ss = 0.0;
  for (int i = 0; i < Nd; ++i) {
    float w = W[(size_t)i * Md + col];
    ss = fma((double)w, (double)w, ss);
  }
  cnorm[col] = (float)sqrt(ss);
}

__global__ __launch_bounds__(256) void k_normalize(const float* __restrict__ W,
                                                   const float* __restrict__ cnorm,
                                                   float* __restrict__ Wn) {
  int idx = blockIdx.x * 256 + threadIdx.x;  // 512*1024
  Wn[idx] = W[idx] / cnorm[idx & (Md - 1)];
}

__global__ __launch_bounds__(256) void k_yn2(const float* __restrict__ Y,
                                             double* __restrict__ dacc) {
  double s = 0.0;
  for (int i = blockIdx.x * 256 + threadIdx.x; i < Bd * Nd; i += gridDim.x * 256) {
    float y = Y[i];
    s = fma((double)y, (double)y, s);
  }
  s = wave_reduce_d(s);
  __shared__ double red[4];
  int lane = threadIdx.x & 63, wid = threadIdx.x >> 6;
  if (lane == 0) red[wid] = s;
  __syncthreads();
  if (threadIdx.x == 0) atomicAdd(&dacc[0], red[0] + red[1] + red[2] + red[3]);
}

// C[m,n] = scale * sum_k A(m,k)*B(k,n); ta/tb: operand stored transposed.
// BMxBN tile, 256 threads, 4xTN per thread, BK=32, register double-buffered
// staging. Per-element accumulation is k0-ascending, kk-ascending ->
// bit-identical to R1/R3 kernels.
template <int BM, int BN, int TN>
__global__ __launch_bounds__(256) void k_gemm_t(const float* __restrict__ A, int lda, int ta,
                                                const float* __restrict__ B, int ldb, int tb,
                                                float* __restrict__ C, int ldc, int Kd,
                                                float scale) {
  constexpr int AE = 32 * BM / 256;
  constexpr int BE = 32 * BN / 256;
  __shared__ __align__(16) float As[32][BM + 4];  // [kk][m]
  __shared__ __align__(16) float Bs[32][BN + 4];  // [kk][n]
  const int tid = threadIdx.x;
  const int tx = tid % (BN / TN), ty = tid / (BN / TN);
  const int m0 = blockIdx.y * BM, n0 = blockIdx.x * BN;
  float ra[AE], rb[BE];
  float acc[4][TN];
#pragma unroll
  for (int i = 0; i < 4; ++i)
#pragma unroll
    for (int j = 0; j < TN; ++j) acc[i][j] = 0.f;

  auto loadA = [&](int k0) {
    if (!ta) {
      const int c = tid & 31, r0 = tid >> 5;
#pragma unroll
      for (int i = 0; i < AE; ++i)
        ra[i] = A[(size_t)(m0 + r0 + i * 8) * lda + (k0 + c)];
    } else {
      const int r = tid % BM, c0 = tid / BM;
#pragma unroll
      for (int i = 0; i < AE; ++i)
        ra[i] = A[(size_t)(k0 + c0 + i * (256 / BM)) * lda + (m0 + r)];
    }
  };
  auto storeA = [&]() {
    if (!ta) {
      const int c = tid & 31, r0 = tid >> 5;
#pragma unroll
      for (int i = 0; i < AE; ++i) As[c][r0 + i * 8] = ra[i];
    } else {
      const int r = tid % BM, c0 = tid / BM;
#pragma unroll
      for (int i = 0; i < AE; ++i) As[c0 + i * (256 / BM)][r] = ra[i];
    }
  };
  auto loadB = [&](int k0) {
    if (!tb) {
      const int c = tid % BN, r0 = tid / BN;
#pragma unroll
      for (int i = 0; i < BE; ++i)
        rb[i] = B[(size_t)(k0 + r0 + i * (256 / BN)) * ldb + (n0 + c)];
    } else {
      const int r = tid & 31, c0 = tid >> 5;
#pragma unroll
      for (int i = 0; i < BE; ++i)
        rb[i] = B[(size_t)(n0 + c0 + i * 8) * ldb + (k0 + r)];
    }
  };
  auto storeB = [&]() {
    if (!tb) {
      const int c = tid % BN, r0 = tid / BN;
#pragma unroll
      for (int i = 0; i < BE; ++i) Bs[r0 + i * (256 / BN)][c] = rb[i];
    } else {
      const int r = tid & 31, c0 = tid >> 5;
#pragma unroll
      for (int i = 0; i < BE; ++i) Bs[r][c0 + i * 8] = rb[i];
    }
  };

  loadA(0);
  loadB(0);
  storeA();
  storeB();
  __syncthreads();
  for (int k0 = 0; k0 < Kd; k0 += 32) {
    const bool more = (k0 + 32) < Kd;
    if (more) { loadA(k0 + 32); loadB(k0 + 32); }  // prefetch into regs
#pragma unroll
    for (int kk = 0; kk < 32; ++kk) {
      const float4 a4 = *(const float4*)&As[kk][ty * 4];
      const float aa[4] = {a4.x, a4.y, a4.z, a4.w};
      float bb[TN];
      if constexpr (TN == 4) {
        const float4 b4 = *(const float4*)&Bs[kk][tx * 4];
        bb[0] = b4.x; bb[1] = b4.y; bb[2] = b4.z; bb[3] = b4.w;
      } else {
        const float2 b2 = *(const float2*)&Bs[kk][tx * 2];
        bb[0] = b2.x; bb[1] = b2.y;
      }
#pragma unroll
      for (int i = 0; i < 4; ++i)
#pragma unroll
        for (int j = 0; j < TN; ++j) acc[i][j] = fmaf(aa[i], bb[j], acc[i][j]);
    }
    if (more) {
      __syncthreads();
      storeA();
      storeB();
      __syncthreads();
    }
  }
#pragma unroll
  for (int i = 0; i < 4; ++i) {
    if constexpr (TN == 4) {
      float4 o;
      o.x = acc[i][0] * scale; o.y = acc[i][1] * scale;
      o.z = acc[i][2] * scale; o.w = acc[i][3] * scale;
      *(float4*)&C[(size_t)(m0 + ty * 4 + i) * ldc + n0 + tx * 4] = o;
    } else {
      float2 o;
      o.x = acc[i][0] * scale; o.y = acc[i][1] * scale;
      *(float2*)&C[(size_t)(m0 + ty * 4 + i) * ldc + n0 + tx * 2] = o;
    }
  }
}

// XLA ErfInvF32 (Giles) — matches jax/XLA erf_inv on f32.
DEV float erfinv_xla(float x) {
  float w = -log1pf(-x * x);
  float p;
  if (w < 5.0f) {
    w = w - 2.5f;
    p = 2.81022636e-08f;
    p = fmaf(p, w, 3.43273939e-07f);
    p = fmaf(p, w, -3.5233877e-06f);
    p = fmaf(p, w, -4.39150654e-06f);
    p = fmaf(p, w, 0.00021858087f);
    p = fmaf(p, w, -0.00125372503f);
    p = fmaf(p, w, -0.00417768164f);
    p = fmaf(p, w, 0.246640727f);
    p = fmaf(p, w, 1.50140941f);
  } else {
    w = sqrtf(w) - 3.0f;
    p = -0.000200214257f;
    p = fmaf(p, w, 0.000100950558f);
    p = fmaf(p, w, 0.00134934322f);
    p = fmaf(p, w, -0.00367342844f);
    p = fmaf(p, w, 0.00573950773f);
    p = fmaf(p, w, -0.0076224613f);
    p = fmaf(p, w, 0.00943887047f);
    p = fmaf(p, w, 1.00167406f);
    p = fmaf(p, w, 2.83297682f);
  }
  return p * x;
}

#define TF_ROUND(r)                                  \
  {                                                  \
    x0 += x1;                                        \
    x1 = (x1 << (r)) | (x1 >> (32 - (r)));           \
    x1 ^= x0;                                        \
  }

// X0 = jax.random.normal(jax.random.key(42), (1,1024), f32), bit-exact bits.
__global__ void k_x0(float* __restrict__ X0) {
  unsigned i = threadIdx.x;  // 0..511; counter pair (i, i+512)
  unsigned x0 = i, x1 = i + 512u;
  const unsigned ks0 = 0u, ks1 = 42u, ks2 = 0x1BD11BDAu ^ 42u;
  x0 += ks0; x1 += ks1;
  TF_ROUND(13) TF_ROUND(15) TF_ROUND(26) TF_ROUND(6)  x0 += ks1; x1 += ks2 + 1u;
  TF_ROUND(17) TF_ROUND(29) TF_ROUND(16) TF_ROUND(24) x0 += ks2; x1 += ks0 + 2u;
  TF_ROUND(13) TF_ROUND(15) TF_ROUND(26) TF_ROUND(6)  x0 += ks0; x1 += ks1 + 3u;
  TF_ROUND(17) TF_ROUND(29) TF_ROUND(16) TF_ROUND(24) x0 += ks1; x1 += ks2 + 4u;
  TF_ROUND(13) TF_ROUND(15) TF_ROUND(26) TF_ROUND(6)  x0 += ks2; x1 += ks0 + 5u;
  const float lo = -0.99999994f;      // nextafter(-1, 0) in f32
  const float sqrt2 = 1.41421356237f; // rounds to 0x3FB504F3
  {
    float f = __uint_as_float((x0 >> 9) | 0x3f800000u) - 1.0f;
    float u = fmaxf(lo, f * 2.0f + lo);  // (hi-lo) == 2.0f exactly in f32
    X0[i] = sqrt2 * erfinv_xla(u);
  }
  {
    float f = __uint_as_float((x1 >> 9) | 0x3f800000u) - 1.0f;
    float u = fmaxf(lo, f * 2.0f + lo);
    X0[i + 512] = sqrt2 * erfinv_xla(u);
  }
}

// z0 = X0 @ Wn^T  (512 outputs, dot length 1024). One wave per row.
__global__ __launch_bounds__(256) void k_z0(const float* __restrict__ X0,
                                            const float* __restrict__ Wn,
                                            float* __restrict__ vout) {
  const int lane = threadIdx.x & 63, wid = threadIdx.x >> 6;
  const int row = blockIdx.x * 4 + wid;  // < 512
  const float4* wr = (const float4*)(Wn + (size_t)row * Md);
  const float4* x4 = (const float4*)X0;
  float s = 0.f;
#pragma unroll
  for (int e = 0; e < 4; ++e) {
    const float4 w4 = wr[lane + e * 64];
    const float4 xx = x4[lane + e * 64];
    s = fmaf(w4.x, xx.x, s); s = fmaf(w4.y, xx.y, s);
    s = fmaf(w4.z, xx.z, s); s = fmaf(w4.w, xx.w, s);
  }
  s = wave_reduce_f(s);
  if (lane == 0) vout[row] = s;
}

// vout = (vin @ Msym) * scale ; Msym is 512x512 symmetric. One wave per row.
__global__ __launch_bounds__(256) void k_pmv(const float* __restrict__ Mmat,
                                             const float* __restrict__ vin,
                                             float* __restrict__ vout, float scale) {
  const int lane = threadIdx.x & 63, wid = threadIdx.x >> 6;
  const int row = blockIdx.x * 4 + wid;  // < 512
  const float4* mr = (const float4*)(Mmat + (size_t)row * Nd);
  const float4* v4 = (const float4*)vin;
  float s = 0.f;
#pragma unroll
  for (int e = 0; e < 2; ++e) {
    const float4 m4 = mr[lane + e * 64];
    const float4 xx = v4[lane + e * 64];
    s = fmaf(m4.x, xx.x, s); s = fmaf(m4.y, xx.y, s);
    s = fmaf(m4.z, xx.z, s); s = fmaf(m4.w, xx.w, s);
  }
  s = wave_reduce_f(s);
  if (lane == 0) vout[row] = s * scale;
}

__global__ __launch_bounds__(512) void k_pfinal(const float* __restrict__ v99,
                                                const float* __restrict__ v100,
                                                float* __restrict__ cbuf) {
  __shared__ double r99[8], r100[8];
  const int t = threadIdx.x, lane = t & 63, wid = t >> 6;
  double a = (double)v99[t]; a *= a;
  double b = (double)v100[t]; b *= b;
  a = wave_reduce_d(a);
  b = wave_reduce_d(b);
  if (lane == 0) { r99[wid] = a; r100[wid] = b; }
  __syncthreads();
  if (t == 0) {
    double n99 = 0.0, n100 = 0.0;
    for (int i = 0; i < 8; ++i) { n99 += r99[i]; n100 += r100[i]; }
    float c = (float)(8.0 * sqrt(n100 / n99));  // last pre-norm ||X2||
    cbuf[0] = c;
    cbuf[1] = 1.0f / c;  // eta
  }
}

// ALL IHT iterations fused: one workgroup per batch row, loops it=-1..49.
// Per-iteration math is verbatim R3 k_select (bit-identical): sparse P=Gamma@Q
// gather, norm term (it>=1), U = Gamma - eta*(P-YW), 4-pass radix select of
// the 65th-largest |U|, strict >, ordered compaction into LDS state.
// it==49 writes the dense Gamma row; epilogue = R3 k_norm50 (norms[49] term).
__global__ __launch_bounds__(256) void k_iht_all(
    const float* __restrict__ Q, const float* __restrict__ YW,
    const float* __restrict__ cbuf, float* __restrict__ gdense,
    double* __restrict__ normacc) {
  __shared__ float u[Md];
  __shared__ float sval[Ksp];
  __shared__ int sidx[Ksp];
  __shared__ unsigned hist[256];
  __shared__ unsigned wred[4];
  __shared__ unsigned sel_need, sel_prefix;
  __shared__ double dred[4];
  __shared__ int scnt;

  const int t = threadIdx.x;
  const int b = blockIdx.x;
  const int lane = t & 63, wv = t >> 6;
  const float eta = cbuf[1];
  const float4 yw = ((const float4*)(YW + (size_t)b * Md))[t];  // row resident in regs
  const float4* Q4 = (const float4*)Q;

  for (int it = -1; it < IHT; ++it) {
    if (it >= 0) {
      const int cnt = scnt;
      float4 p = make_float4(0.f, 0.f, 0.f, 0.f);
      int k = 0;
      for (; k + 4 <= cnt; k += 4) {  // 4 loads in flight; fma order k-ascending
        const int i0 = sidx[k], i1 = sidx[k + 1], i2 = sidx[k + 2], i3 = sidx[k + 3];
        const float g0 = sval[k], g1 = sval[k + 1], g2 = sval[k + 2], g3 = sval[k + 3];
        const float4 q0 = Q4[(size_t)i0 * 256 + t];
        const float4 q1 = Q4[(size_t)i1 * 256 + t];
        const float4 q2 = Q4[(size_t)i2 * 256 + t];
        const float4 q3 = Q4[(size_t)i3 * 256 + t];
        p.x = fmaf(g0, q0.x, p.x); p.x = fmaf(g1, q1.x, p.x);
        p.x = fmaf(g2, q2.x, p.x); p.x = fmaf(g3, q3.x, p.x);
        p.y = fmaf(g0, q0.y, p.y); p.y = fmaf(g1, q1.y, p.y);
        p.y = fmaf(g2, q2.y, p.y); p.y = fmaf(g3, q3.y, p.y);
        p.z = fmaf(g0, q0.z, p.z); p.z = fmaf(g1, q1.z, p.z);
        p.z = fmaf(g2, q2.z, p.z); p.z = fmaf(g3, q3.z, p.z);
        p.w = fmaf(g0, q0.w, p.w); p.w = fmaf(g1, q1.w, p.w);
        p.w = fmaf(g2, q2.w, p.w); p.w = fmaf(g3, q3.w, p.w);
      }
      for (; k < cnt; ++k) {
        const int id = sidx[k];
        const float g = sval[k];
        const float4 q = Q4[(size_t)id * 256 + t];
        p.x = fmaf(g, q.x, p.x); p.y = fmaf(g, q.y, p.y);
        p.z = fmaf(g, q.z, p.z); p.w = fmaf(g, q.w, p.w);
      }
      ((float4*)u)[t] = p;  // u holds P for the norm dot
      __syncthreads();
      if (it >= 1) {
        double part = 0.0;
        if (t < cnt) {
          const int id = sidx[t];
          part = (double)sval[t] * ((double)u[id] - 2.0 * (double)YW[(size_t)b * Md + id]);
        }
        part = wave_reduce_d(part);
        if (lane == 0) dred[wv] = part;
        __syncthreads();
        if (t == 0) atomicAdd(&normacc[it - 1], dred[0] + dred[1] + dred[2] + dred[3]);
        __syncthreads();
      }
      float4 uu;
      uu.x = -(eta * (p.x - yw.x)); uu.y = -(eta * (p.y - yw.y));
      uu.z = -(eta * (p.z - yw.z)); uu.w = -(eta * (p.w - yw.w));
      ((float4*)u)[t] = uu;
      __syncthreads();
      if (t < cnt) u[sidx[t]] += sval[t];  // distinct indices, no race
      __syncthreads();
    } else {
      float4 uu;
      uu.x = eta * yw.x; uu.y = eta * yw.y; uu.z = eta * yw.z; uu.w = eta * yw.w;
      ((float4*)u)[t] = uu;
      __syncthreads();
    }

    // keys/vals in registers for all passes + compaction
    float vals[4];
    unsigned key[4];
    {
      const float4 mv = ((const float4*)u)[t];
      vals[0] = mv.x; vals[1] = mv.y; vals[2] = mv.z; vals[3] = mv.w;
#pragma unroll
      for (int e = 0; e < 4; ++e) key[e] = __float_as_uint(vals[e]) & 0x7fffffffu;
    }

    // ---- radix select: exact bit pattern of the (K+1)-th largest |u| ----
    unsigned need = Ksp + 1, prefix = 0u, pmask = 0u;
    for (int pass = 3; pass >= 0; --pass) {
      const int sh = 8 * pass;
      hist[t] = 0u;
      __syncthreads();
#pragma unroll
      for (int e = 0; e < 4; ++e)
        if ((key[e] & pmask) == prefix) atomicAdd(&hist[(key[e] >> sh) & 255u], 1u);
      __syncthreads();
      const unsigned h = hist[t];
      unsigned x = h;
#pragma unroll
      for (int off = 1; off < 64; off <<= 1) {  // wave-level inclusive suffix scan
        const unsigned y = __shfl_down(x, off);
        if (lane + off < 64) x += y;
      }
      if (lane == 0) wred[wv] = x;  // wave total
      __syncthreads();
      unsigned addhi = 0u;
      for (int w2 = wv + 1; w2 < 4; ++w2) addhi += wred[w2];
      const unsigned incl = x + addhi;      // count of keys with bin >= t
      const unsigned excl = incl - h;       // count of keys with bin >  t
      if (incl >= need && excl < need) {
        sel_prefix = prefix | ((unsigned)t << sh);
        sel_need = need - excl;
      }
      __syncthreads();
      prefix = sel_prefix;
      need = sel_need;
      pmask |= (255u << sh);
    }
    const unsigned Tbits = prefix;

    // ---- ordered compaction (deterministic, ascending column order) ----
    unsigned keep = 0u;
    unsigned myc = 0u;
#pragma unroll
    for (int e = 0; e < 4; ++e)
      if (key[e] > Tbits) { keep |= (1u << e); ++myc; }
    unsigned x = myc;
#pragma unroll
    for (int off = 1; off < 64; off <<= 1) {  // wave-level inclusive prefix scan
      const unsigned y = __shfl_up(x, off);
      if (lane >= off) x += y;
    }
    __syncthreads();               // wred reuse: prior reads complete
    if (lane == 63) wred[wv] = x;  // wave total
    __syncthreads();
    unsigned addlo = 0u;
    for (int w2 = 0; w2 < wv; ++w2) addlo += wred[w2];
    int base = (int)(x + addlo) - (int)myc;  // exclusive prefix in thread order
#pragma unroll
    for (int e = 0; e < 4; ++e) {
      if (keep & (1u << e)) {
        sidx[base] = t * 4 + e;
        sval[base] = vals[e];
        ++base;
      }
    }
    if (t == 0) scnt = (int)(wred[0] + wred[1] + wred[2] + wred[3]);
    if (it == IHT - 1) {
      float4 g;
      g.x = (keep & 1u) ? vals[0] : 0.f;
      g.y = (keep & 2u) ? vals[1] : 0.f;
      g.z = (keep & 4u) ? vals[2] : 0.f;
      g.w = (keep & 8u) ? vals[3] : 0.f;
      ((float4*)(gdense + (size_t)b * Md))[t] = g;
    }
    __syncthreads();  // publish sidx/sval/scnt for next iteration
  }

  // ---- epilogue: norms[49] term for Gamma_51 (verbatim R3 k_norm50 math) ----
  const int cnt = scnt;
  if (wv == 0) {
    double part = 0.0;
    if (lane < cnt) {
      const int id = sidx[lane];
      float acc2 = 0.f;
      for (int k = 0; k < cnt; ++k)
        acc2 = fmaf(sval[k], Q[(size_t)sidx[k] * Md + id], acc2);
      part = (double)sval[lane] * ((double)acc2 - 2.0 * (double)YW[(size_t)b * Md + id]);
    }
    part = wave_reduce_d(part);
    if (lane == 0) atomicAdd(&normacc[IHT - 1], part);
  }
}

__global__ void k_wnorms(const double* __restrict__ dacc, float* __restrict__ onorms) {
  const int t = threadIdx.x;
  if (t < IHT) {
    const double yn2 = dacc[0];
    double r2 = yn2 + dacc[1 + t];
    if (r2 < 0.0) r2 = 0.0;
    onorms[t] = (float)(sqrt(r2) / sqrt(yn2));
  }
}

extern "C" void kernel_launch(void* const* d_in, const int* in_sizes, int n_in,
                              void* d_out, int out_size, void* d_ws, size_t ws_size,
                              hipStream_t stream) {
  (void)in_sizes; (void)n_in; (void)out_size; (void)ws_size;  // K hardcoded = 64
  const float* Y = (const float*)d_in[0];  // [1024,512]
  const float* W = (const float*)d_in[1];  // [512,1024]
  float* out = (float*)d_out;
  float* outX = out;                   // [512,1024]
  float* outG = out + Nd * Md;         // [1024,1024]
  float* outN = outG + Bd * Md;        // [50]

  // workspace layout (~11.5 MB)
  char* wsb = (char*)d_ws;
  double* dacc = (double*)wsb;               // 51 doubles
  float* cbuf = (float*)(wsb + 512);         // [0]=c, [1]=eta
  float* Wn = (float*)(wsb + 1024);          // 512*1024
  float* Q = Wn + Nd * Md;                   // 1024*1024
  float* YW = Q + Md * Md;                   // 1024*1024
  float* Smat = YW + Bd * Md;                // 512*512
  float* S2 = Smat + Nd * Nd;                // 512*512
  float* cnorm = S2 + Nd * Nd;               // 1024
  float* X0 = cnorm + Md;                    // 1024
  float* V = X0 + Md;                        // 4*512 power-iter slots

  k_zero<<<1, 64, 0, stream>>>(dacc);
  k_colnorm<<<4, 256, 0, stream>>>(W, cnorm);
  k_normalize<<<2048, 256, 0, stream>>>(W, cnorm, Wn);

  // S = Wn Wn^T (512x512, K=1024); S2 = S*S/64; Q = Wn^T Wn (K=512); YW = Y Wn
  k_gemm_t<64, 32, 2><<<dim3(16, 8), 256, 0, stream>>>(Wn, Md, 0, Wn, Md, 1, Smat, Nd, Md, 1.0f);
  k_gemm_t<64, 32, 2><<<dim3(16, 8), 256, 0, stream>>>(Smat, Nd, 0, Smat, Nd, 0, S2, Nd, Nd, 0.015625f);
  k_gemm_t<64, 64, 4><<<dim3(16, 16), 256, 0, stream>>>(Wn, Md, 1, Wn, Md, 0, Q, Md, Nd, 1.0f);
  k_gemm_t<64, 64, 4><<<dim3(16, 16), 256, 0, stream>>>(Y, Nd, 0, Wn, Md, 0, YW, Md, Nd, 1.0f);
  k_yn2<<<128, 256, 0, stream>>>(Y, dacc);

  // power method in Z-space: z0 = X0 @ Wn^T; 49 steps of S2, 2 steps of S/8
  // (untouched from R3 — eta must stay bit-identical)
  k_x0<<<1, 512, 0, stream>>>(X0);
  k_z0<<<128, 256, 0, stream>>>(X0, Wn, V);
  float* pin = V;
  float* pout = V + 512;
  for (int i = 0; i < 49; ++i) {
    k_pmv<<<128, 256, 0, stream>>>(S2, pin, pout, 1.0f);
    float* tp = pin; pin = pout; pout = tp;
  }
  k_pmv<<<128, 256, 0, stream>>>(Smat, pin, V + 1024, 0.125f);        // v99
  k_pmv<<<128, 256, 0, stream>>>(Smat, V + 1024, V + 1536, 0.125f);   // v100
  k_pfinal<<<1, 512, 0, stream>>>(V + 1024, V + 1536, cbuf);

  // IHT: init + 50 iterations + final norm term, all in ONE launch
  k_iht_all<<<1024, 256, 0, stream>>>(Q, YW, cbuf, outG, dacc + 1);
  k_wnorms<<<1, 64, 0, stream>>>(dacc, outN);

  // X = Wn @ Gamma (512x1024, K=1024) reading dense Gamma from d_out
  k_gemm_t<64, 32, 2><<<dim3(32, 8), 256, 0, stream>>>(Wn, Md, 0, outG, Md, 0, outX, Md, Md, 1.0f);
}

// Round 5
// 978.224 us; speedup vs baseline: 1.9485x; 1.1174x over previous
//
#include <hip/hip_runtime.h>

// DictLearn: W column-normalize -> power method (100 it) -> IHT sparse coding
// (50 it, K=64 hard threshold) -> X = W @ Gamma.
// Outputs in d_out: X [512*1024] fp32, Gamma [1024*1024] fp32, norms [50] fp32.
//
// R5 changes vs R4 (trajectory bit-identical: fmaf chains, select integer math,
// and eta untouched):
//  * k_iht_all select: 14 barriers/iter (was 24) — per-wave double-buffered
//    histograms (zeroing overlapped, no extra barrier), wave-0-local redundant
//    suffix scans replace cross-wave LDS wred round-trips.
//  * gather scalarized: readfirstlane(sidx/sval) -> SGPR base + t*16 voffset
//    (saddr global_load_dwordx4), unroll 8 for deeper memory-level parallelism.
//  * YW row cached in LDS (yws) for the norm-dot scattered reads.

#define DEV __device__ __forceinline__

constexpr int Nd = 512;    // signal dim
constexpr int Md = 1024;   // atoms
constexpr int Bd = 1024;   // batch
constexpr int Ksp = 64;    // sparsity K
constexpr int IHT = 50;

DEV float wave_reduce_f(float v) {
#pragma unroll
  for (int off = 32; off > 0; off >>= 1) v += __shfl_down(v, off);
  return v;
}
DEV double wave_reduce_d(double v) {
#pragma unroll
  for (int off = 32; off > 0; off >>= 1) v += __shfl_down(v, off);
  return v;
}
DEV float rfl_f(float v) {
  return __uint_as_float(__builtin_amdgcn_readfirstlane(__float_as_uint(v)));
}

__global__ void k_zero(double* dacc) {
  int t = threadIdx.x;
  if (t < 51) dacc[t] = 0.0;  // [0]=Yn2, [1..50]=norm accumulators
}

__global__ __launch_bounds__(256) void k_colnorm(const float* __restrict__ W,
                                                 float* __restrict__ cnorm) {
  int col = blockIdx.x * 256 + threadIdx.x;  // 1024 cols
  double ss = 0.0;
  for (int i = 0; i < Nd; ++i) {
    float w = W[(size_t)i * Md + col];
    ss = fma((double)w, (double)w, ss);
  }
  cnorm[col] = (float)sqrt(ss);
}

__global__ __launch_bounds__(256) void k_normalize(const float* __restrict__ W,
                                                   const float* __restrict__ cnorm,
                                                   float* __restrict__ Wn) {
  int idx = blockIdx.x * 256 + threadIdx.x;  // 512*1024
  Wn[idx] = W[idx] / cnorm[idx & (Md - 1)];
}

__global__ __launch_bounds__(256) void k_yn2(const float* __restrict__ Y,
                                             double* __restrict__ dacc) {
  double s = 0.0;
  for (int i = blockIdx.x * 256 + threadIdx.x; i < Bd * Nd; i += gridDim.x * 256) {
    float y = Y[i];
    s = fma((double)y, (double)y, s);
  }
  s = wave_reduce_d(s);
  __shared__ double red[4];
  int lane = threadIdx.x & 63, wid = threadIdx.x >> 6;
  if (lane == 0) red[wid] = s;
  __syncthreads();
  if (threadIdx.x == 0) atomicAdd(&dacc[0], red[0] + red[1] + red[2] + red[3]);
}

// C[m,n] = scale * sum_k A(m,k)*B(k,n); ta/tb: operand stored transposed.
// BMxBN tile, 256 threads, 4xTN per thread, BK=32, register double-buffered
// staging. Per-element accumulation k0-ascending, kk-ascending (bit-stable).
template <int BM, int BN, int TN>
__global__ __launch_bounds__(256) void k_gemm_t(const float* __restrict__ A, int lda, int ta,
                                                const float* __restrict__ B, int ldb, int tb,
                                                float* __restrict__ C, int ldc, int Kd,
                                                float scale) {
  constexpr int AE = 32 * BM / 256;
  constexpr int BE = 32 * BN / 256;
  __shared__ __align__(16) float As[32][BM + 4];  // [kk][m]
  __shared__ __align__(16) float Bs[32][BN + 4];  // [kk][n]
  const int tid = threadIdx.x;
  const int tx = tid % (BN / TN), ty = tid / (BN / TN);
  const int m0 = blockIdx.y * BM, n0 = blockIdx.x * BN;
  float ra[AE], rb[BE];
  float acc[4][TN];
#pragma unroll
  for (int i = 0; i < 4; ++i)
#pragma unroll
    for (int j = 0; j < TN; ++j) acc[i][j] = 0.f;

  auto loadA = [&](int k0) {
    if (!ta) {
      const int c = tid & 31, r0 = tid >> 5;
#pragma unroll
      for (int i = 0; i < AE; ++i)
        ra[i] = A[(size_t)(m0 + r0 + i * 8) * lda + (k0 + c)];
    } else {
      const int r = tid % BM, c0 = tid / BM;
#pragma unroll
      for (int i = 0; i < AE; ++i)
        ra[i] = A[(size_t)(k0 + c0 + i * (256 / BM)) * lda + (m0 + r)];
    }
  };
  auto storeA = [&]() {
    if (!ta) {
      const int c = tid & 31, r0 = tid >> 5;
#pragma unroll
      for (int i = 0; i < AE; ++i) As[c][r0 + i * 8] = ra[i];
    } else {
      const int r = tid % BM, c0 = tid / BM;
#pragma unroll
      for (int i = 0; i < AE; ++i) As[c0 + i * (256 / BM)][r] = ra[i];
    }
  };
  auto loadB = [&](int k0) {
    if (!tb) {
      const int c = tid % BN, r0 = tid / BN;
#pragma unroll
      for (int i = 0; i < BE; ++i)
        rb[i] = B[(size_t)(k0 + r0 + i * (256 / BN)) * ldb + (n0 + c)];
    } else {
      const int r = tid & 31, c0 = tid >> 5;
#pragma unroll
      for (int i = 0; i < BE; ++i)
        rb[i] = B[(size_t)(n0 + c0 + i * 8) * ldb + (k0 + r)];
    }
  };
  auto storeB = [&]() {
    if (!tb) {
      const int c = tid % BN, r0 = tid / BN;
#pragma unroll
      for (int i = 0; i < BE; ++i) Bs[r0 + i * (256 / BN)][c] = rb[i];
    } else {
      const int r = tid & 31, c0 = tid >> 5;
#pragma unroll
      for (int i = 0; i < BE; ++i) Bs[r][c0 + i * 8] = rb[i];
    }
  };

  loadA(0);
  loadB(0);
  storeA();
  storeB();
  __syncthreads();
  for (int k0 = 0; k0 < Kd; k0 += 32) {
    const bool more = (k0 + 32) < Kd;
    if (more) { loadA(k0 + 32); loadB(k0 + 32); }  // prefetch into regs
#pragma unroll
    for (int kk = 0; kk < 32; ++kk) {
      const float4 a4 = *(const float4*)&As[kk][ty * 4];
      const float aa[4] = {a4.x, a4.y, a4.z, a4.w};
      float bb[TN];
      if constexpr (TN == 4) {
        const float4 b4 = *(const float4*)&Bs[kk][tx * 4];
        bb[0] = b4.x; bb[1] = b4.y; bb[2] = b4.z; bb[3] = b4.w;
      } else {
        const float2 b2 = *(const float2*)&Bs[kk][tx * 2];
        bb[0] = b2.x; bb[1] = b2.y;
      }
#pragma unroll
      for (int i = 0; i < 4; ++i)
#pragma unroll
        for (int j = 0; j < TN; ++j) acc[i][j] = fmaf(aa[i], bb[j], acc[i][j]);
    }
    if (more) {
      __syncthreads();
      storeA();
      storeB();
      __syncthreads();
    }
  }
#pragma unroll
  for (int i = 0; i < 4; ++i) {
    if constexpr (TN == 4) {
      float4 o;
      o.x = acc[i][0] * scale; o.y = acc[i][1] * scale;
      o.z = acc[i][2] * scale; o.w = acc[i][3] * scale;
      *(float4*)&C[(size_t)(m0 + ty * 4 + i) * ldc + n0 + tx * 4] = o;
    } else {
      float2 o;
      o.x = acc[i][0] * scale; o.y = acc[i][1] * scale;
      *(float2*)&C[(size_t)(m0 + ty * 4 + i) * ldc + n0 + tx * 2] = o;
    }
  }
}

// XLA ErfInvF32 (Giles) — matches jax/XLA erf_inv on f32.
DEV float erfinv_xla(float x) {
  float w = -log1pf(-x * x);
  float p;
  if (w < 5.0f) {
    w = w - 2.5f;
    p = 2.81022636e-08f;
    p = fmaf(p, w, 3.43273939e-07f);
    p = fmaf(p, w, -3.5233877e-06f);
    p = fmaf(p, w, -4.39150654e-06f);
    p = fmaf(p, w, 0.00021858087f);
    p = fmaf(p, w, -0.00125372503f);
    p = fmaf(p, w, -0.00417768164f);
    p = fmaf(p, w, 0.246640727f);
    p = fmaf(p, w, 1.50140941f);
  } else {
    w = sqrtf(w) - 3.0f;
    p = -0.000200214257f;
    p = fmaf(p, w, 0.000100950558f);
    p = fmaf(p, w, 0.00134934322f);
    p = fmaf(p, w, -0.00367342844f);
    p = fmaf(p, w, 0.00573950773f);
    p = fmaf(p, w, -0.0076224613f);
    p = fmaf(p, w, 0.00943887047f);
    p = fmaf(p, w, 1.00167406f);
    p = fmaf(p, w, 2.83297682f);
  }
  return p * x;
}

#define TF_ROUND(r)                                  \
  {                                                  \
    x0 += x1;                                        \
    x1 = (x1 << (r)) | (x1 >> (32 - (r)));           \
    x1 ^= x0;                                        \
  }

// X0 = jax.random.normal(jax.random.key(42), (1,1024), f32), bit-exact bits.
__global__ void k_x0(float* __restrict__ X0) {
  unsigned i = threadIdx.x;  // 0..511; counter pair (i, i+512)
  unsigned x0 = i, x1 = i + 512u;
  const unsigned ks0 = 0u, ks1 = 42u, ks2 = 0x1BD11BDAu ^ 42u;
  x0 += ks0; x1 += ks1;
  TF_ROUND(13) TF_ROUND(15) TF_ROUND(26) TF_ROUND(6)  x0 += ks1; x1 += ks2 + 1u;
  TF_ROUND(17) TF_ROUND(29) TF_ROUND(16) TF_ROUND(24) x0 += ks2; x1 += ks0 + 2u;
  TF_ROUND(13) TF_ROUND(15) TF_ROUND(26) TF_ROUND(6)  x0 += ks0; x1 += ks1 + 3u;
  TF_ROUND(17) TF_ROUND(29) TF_ROUND(16) TF_ROUND(24) x0 += ks1; x1 += ks2 + 4u;
  TF_ROUND(13) TF_ROUND(15) TF_ROUND(26) TF_ROUND(6)  x0 += ks2; x1 += ks0 + 5u;
  const float lo = -0.99999994f;      // nextafter(-1, 0) in f32
  const float sqrt2 = 1.41421356237f; // rounds to 0x3FB504F3
  {
    float f = __uint_as_float((x0 >> 9) | 0x3f800000u) - 1.0f;
    float u = fmaxf(lo, f * 2.0f + lo);  // (hi-lo) == 2.0f exactly in f32
    X0[i] = sqrt2 * erfinv_xla(u);
  }
  {
    float f = __uint_as_float((x1 >> 9) | 0x3f800000u) - 1.0f;
    float u = fmaxf(lo, f * 2.0f + lo);
    X0[i + 512] = sqrt2 * erfinv_xla(u);
  }
}

// z0 = X0 @ Wn^T  (512 outputs, dot length 1024). One wave per row.
__global__ __launch_bounds__(256) void k_z0(const float* __restrict__ X0,
                                            const float* __restrict__ Wn,
                                            float* __restrict__ vout) {
  const int lane = threadIdx.x & 63, wid = threadIdx.x >> 6;
  const int row = blockIdx.x * 4 + wid;  // < 512
  const float4* wr = (const float4*)(Wn + (size_t)row * Md);
  const float4* x4 = (const float4*)X0;
  float s = 0.f;
#pragma unroll
  for (int e = 0; e < 4; ++e) {
    const float4 w4 = wr[lane + e * 64];
    const float4 xx = x4[lane + e * 64];
    s = fmaf(w4.x, xx.x, s); s = fmaf(w4.y, xx.y, s);
    s = fmaf(w4.z, xx.z, s); s = fmaf(w4.w, xx.w, s);
  }
  s = wave_reduce_f(s);
  if (lane == 0) vout[row] = s;
}

// vout = (vin @ Msym) * scale ; Msym is 512x512 symmetric. One wave per row.
__global__ __launch_bounds__(256) void k_pmv(const float* __restrict__ Mmat,
                                             const float* __restrict__ vin,
                                             float* __restrict__ vout, float scale) {
  const int lane = threadIdx.x & 63, wid = threadIdx.x >> 6;
  const int row = blockIdx.x * 4 + wid;  // < 512
  const float4* mr = (const float4*)(Mmat + (size_t)row * Nd);
  const float4* v4 = (const float4*)vin;
  float s = 0.f;
#pragma unroll
  for (int e = 0; e < 2; ++e) {
    const float4 m4 = mr[lane + e * 64];
    const float4 xx = v4[lane + e * 64];
    s = fmaf(m4.x, xx.x, s); s = fmaf(m4.y, xx.y, s);
    s = fmaf(m4.z, xx.z, s); s = fmaf(m4.w, xx.w, s);
  }
  s = wave_reduce_f(s);
  if (lane == 0) vout[row] = s * scale;
}

__global__ __launch_bounds__(512) void k_pfinal(const float* __restrict__ v99,
                                                const float* __restrict__ v100,
                                                float* __restrict__ cbuf) {
  __shared__ double r99[8], r100[8];
  const int t = threadIdx.x, lane = t & 63, wid = t >> 6;
  double a = (double)v99[t]; a *= a;
  double b = (double)v100[t]; b *= b;
  a = wave_reduce_d(a);
  b = wave_reduce_d(b);
  if (lane == 0) { r99[wid] = a; r100[wid] = b; }
  __syncthreads();
  if (t == 0) {
    double n99 = 0.0, n100 = 0.0;
    for (int i = 0; i < 8; ++i) { n99 += r99[i]; n100 += r100[i]; }
    float c = (float)(8.0 * sqrt(n100 / n99));  // last pre-norm ||X2||
    cbuf[0] = c;
    cbuf[1] = 1.0f / c;  // eta
  }
}

// ALL IHT iterations fused: one workgroup per batch row, loops it=-1..49.
// Math identical to R4 (bit-exact): sparse P=Gamma@Q gather, norm term,
// U = Gamma - eta*(P-YW), 4-pass radix select (strict >), ordered compaction.
// R5: scalarized gather (saddr loads), 2-barrier radix passes with per-wave
// double-buffered histograms, wave-0 redundant suffix scans, YW row in LDS.
__global__ __launch_bounds__(256) void k_iht_all(
    const float* __restrict__ Q, const float* __restrict__ YW,
    const float* __restrict__ cbuf, float* __restrict__ gdense,
    double* __restrict__ normacc) {
  __shared__ float u[Md];
  __shared__ float yws[Md];
  __shared__ float sval[Ksp];
  __shared__ int sidx[Ksp];
  __shared__ unsigned histbuf[2][4][256];  // [parity][wave][bin]
  __shared__ unsigned wred[4];
  __shared__ unsigned sel_need, sel_prefix;
  __shared__ double dred[4];
  __shared__ int scnt;

  const int t = threadIdx.x;
  const int b = blockIdx.x;
  const int lane = t & 63, wv = t >> 6;
  const float eta = cbuf[1];
  const float4 yw = ((const float4*)(YW + (size_t)b * Md))[t];  // row in regs
  ((float4*)yws)[t] = yw;                                        // + LDS copy
#pragma unroll
  for (int e = 0; e < 8; ++e) ((unsigned*)histbuf)[t + e * 256] = 0u;
  const float* Qt = Q + t * 4;  // per-thread column base; row base is scalar

  for (int it = -1; it < IHT; ++it) {
    if (it >= 0) {
      const int cnt = scnt;
      float4 p = make_float4(0.f, 0.f, 0.f, 0.f);
      int k = 0;
      for (; k + 8 <= cnt; k += 8) {  // 8 saddr loads in flight; k-ascending fma
#define GROW(j)                                                        \
        const int id##j = __builtin_amdgcn_readfirstlane(sidx[k + j]); \
        const float g##j = rfl_f(sval[k + j]);                         \
        const float4 q##j = *(const float4*)(Qt + (size_t)id##j * Md);
        GROW(0) GROW(1) GROW(2) GROW(3) GROW(4) GROW(5) GROW(6) GROW(7)
#undef GROW
        p.x = fmaf(g0, q0.x, p.x); p.x = fmaf(g1, q1.x, p.x);
        p.x = fmaf(g2, q2.x, p.x); p.x = fmaf(g3, q3.x, p.x);
        p.x = fmaf(g4, q4.x, p.x); p.x = fmaf(g5, q5.x, p.x);
        p.x = fmaf(g6, q6.x, p.x); p.x = fmaf(g7, q7.x, p.x);
        p.y = fmaf(g0, q0.y, p.y); p.y = fmaf(g1, q1.y, p.y);
        p.y = fmaf(g2, q2.y, p.y); p.y = fmaf(g3, q3.y, p.y);
        p.y = fmaf(g4, q4.y, p.y); p.y = fmaf(g5, q5.y, p.y);
        p.y = fmaf(g6, q6.y, p.y); p.y = fmaf(g7, q7.y, p.y);
        p.z = fmaf(g0, q0.z, p.z); p.z = fmaf(g1, q1.z, p.z);
        p.z = fmaf(g2, q2.z, p.z); p.z = fmaf(g3, q3.z, p.z);
        p.z = fmaf(g4, q4.z, p.z); p.z = fmaf(g5, q5.z, p.z);
        p.z = fmaf(g6, q6.z, p.z); p.z = fmaf(g7, q7.z, p.z);
        p.w = fmaf(g0, q0.w, p.w); p.w = fmaf(g1, q1.w, p.w);
        p.w = fmaf(g2, q2.w, p.w); p.w = fmaf(g3, q3.w, p.w);
        p.w = fmaf(g4, q4.w, p.w); p.w = fmaf(g5, q5.w, p.w);
        p.w = fmaf(g6, q6.w, p.w); p.w = fmaf(g7, q7.w, p.w);
      }
      for (; k < cnt; ++k) {
        const int id = __builtin_amdgcn_readfirstlane(sidx[k]);
        const float g = rfl_f(sval[k]);
        const float4 q = *(const float4*)(Qt + (size_t)id * Md);
        p.x = fmaf(g, q.x, p.x); p.y = fmaf(g, q.y, p.y);
        p.z = fmaf(g, q.z, p.z); p.w = fmaf(g, q.w, p.w);
      }
      ((float4*)u)[t] = p;  // u holds P for the norm dot
      __syncthreads();      // B1: P visible
      if (it >= 1) {
        double part = 0.0;
        if (t < cnt) {
          const int id = sidx[t];
          part = (double)sval[t] * ((double)u[id] - 2.0 * (double)yws[id]);
        }
        part = wave_reduce_d(part);
        if (lane == 0) dred[wv] = part;
      }
      __syncthreads();      // B2: dred visible; all u reads done
      if (it >= 1 && t == 0)
        atomicAdd(&normacc[it - 1], dred[0] + dred[1] + dred[2] + dred[3]);
      float4 uu;
      uu.x = -(eta * (p.x - yw.x)); uu.y = -(eta * (p.y - yw.y));
      uu.z = -(eta * (p.z - yw.z)); uu.w = -(eta * (p.w - yw.w));
      ((float4*)u)[t] = uu;
      __syncthreads();      // B3: uu visible
      if (t < cnt) u[sidx[t]] += sval[t];  // distinct indices, no race
      __syncthreads();      // B4
    } else {
      float4 uu;
      uu.x = eta * yw.x; uu.y = eta * yw.y; uu.z = eta * yw.z; uu.w = eta * yw.w;
      ((float4*)u)[t] = uu;
      __syncthreads();      // also publishes yws + histbuf zeros
    }

    // keys/vals in registers for all passes + compaction
    float vals[4];
    unsigned key[4];
    {
      const float4 mv = ((const float4*)u)[t];
      vals[0] = mv.x; vals[1] = mv.y; vals[2] = mv.z; vals[3] = mv.w;
#pragma unroll
      for (int e = 0; e < 4; ++e) key[e] = __float_as_uint(vals[e]) & 0x7fffffffu;
    }

    // ---- radix select: exact bit pattern of the (K+1)-th largest |u| ----
    // 2 barriers/pass: per-wave histograms (atomic contention /4), parity
    // double-buffer (the off buffer is re-zeroed during the compute window),
    // wave 0 does a redundant 256-bin suffix scan locally (no cross-wave LDS).
    unsigned need = Ksp + 1, prefix = 0u, pmask = 0u;
#pragma unroll
    for (int pass = 3; pass >= 0; --pass) {
      const int sh = 8 * pass;
      const int pb = pass & 1;
      unsigned(*hist)[256] = histbuf[pb];
#pragma unroll
      for (int e = 0; e < 4; ++e)
        if ((key[e] & pmask) == prefix) atomicAdd(&hist[wv][(key[e] >> sh) & 255u], 1u);
      __syncthreads();  // A: atomics visible
      // zero the opposite buffer (used by the NEXT pass; its readers finished
      // two barriers ago) — each wave zeroes its own slice
      unsigned* hz = histbuf[pb ^ 1][wv];
      hz[lane] = 0u; hz[lane + 64] = 0u; hz[lane + 128] = 0u; hz[lane + 192] = 0u;
      if (wv == 0) {
        // merged counts for bins lane, lane+64, lane+128, lane+192
        const unsigned c0 = hist[0][lane] + hist[1][lane] + hist[2][lane] + hist[3][lane];
        const unsigned c1 = hist[0][lane + 64] + hist[1][lane + 64] + hist[2][lane + 64] + hist[3][lane + 64];
        const unsigned c2 = hist[0][lane + 128] + hist[1][lane + 128] + hist[2][lane + 128] + hist[3][lane + 128];
        const unsigned c3 = hist[0][lane + 192] + hist[1][lane + 192] + hist[2][lane + 192] + hist[3][lane + 192];
        unsigned s0 = c0, s1 = c1, s2 = c2, s3 = c3;  // suffix scans (4 chunks)
#pragma unroll
        for (int off = 1; off < 64; off <<= 1) {
          const unsigned y0 = __shfl_down(s0, off), y1 = __shfl_down(s1, off);
          const unsigned y2 = __shfl_down(s2, off), y3 = __shfl_down(s3, off);
          if (lane + off < 64) { s0 += y0; s1 += y1; s2 += y2; s3 += y3; }
        }
        const unsigned T1 = __builtin_amdgcn_readfirstlane(s1);
        const unsigned T2 = __builtin_amdgcn_readfirstlane(s2);
        const unsigned T3 = __builtin_amdgcn_readfirstlane(s3);
        const unsigned i0 = s0 + T1 + T2 + T3;  // incl count, bin = lane
        const unsigned i1 = s1 + T2 + T3;       // bin = lane+64
        const unsigned i2 = s2 + T3;            // bin = lane+128
        const unsigned i3 = s3;                 // bin = lane+192
        if (i0 >= need && i0 - c0 < need) { sel_prefix = prefix | ((unsigned)lane << sh); sel_need = need - (i0 - c0); }
        if (i1 >= need && i1 - c1 < need) { sel_prefix = prefix | ((unsigned)(lane + 64) << sh); sel_need = need - (i1 - c1); }
        if (i2 >= need && i2 - c2 < need) { sel_prefix = prefix | ((unsigned)(lane + 128) << sh); sel_need = need - (i2 - c2); }
        if (i3 >= need && i3 - c3 < need) { sel_prefix = prefix | ((unsigned)(lane + 192) << sh); sel_need = need - (i3 - c3); }
      }
      __syncthreads();  // B: sel_* and zeros visible
      prefix = sel_prefix;
      need = sel_need;
      pmask |= (255u << sh);
    }
    const unsigned Tbits = prefix;

    // ---- ordered compaction (deterministic, ascending column order) ----
    unsigned keep = 0u;
    unsigned myc = 0u;
#pragma unroll
    for (int e = 0; e < 4; ++e)
      if (key[e] > Tbits) { keep |= (1u << e); ++myc; }
    unsigned x = myc;
#pragma unroll
    for (int off = 1; off < 64; off <<= 1) {  // wave inclusive prefix scan
      const unsigned y = __shfl_up(x, off);
      if (lane >= off) x += y;
    }
    if (lane == 63) wred[wv] = x;  // wave total
    __syncthreads();  // C1: wred visible (old sidx/sval reads all done pre-B4)
    unsigned addlo = 0u;
    for (int w2 = 0; w2 < wv; ++w2) addlo += wred[w2];
    int base = (int)(x + addlo) - (int)myc;  // exclusive prefix in thread order
#pragma unroll
    for (int e = 0; e < 4; ++e) {
      if (keep & (1u << e)) {
        sidx[base] = t * 4 + e;
        sval[base] = vals[e];
        ++base;
      }
    }
    if (t == 0) scnt = (int)(wred[0] + wred[1] + wred[2] + wred[3]);
    if (it == IHT - 1) {
      float4 g;
      g.x = (keep & 1u) ? vals[0] : 0.f;
      g.y = (keep & 2u) ? vals[1] : 0.f;
      g.z = (keep & 4u) ? vals[2] : 0.f;
      g.w = (keep & 8u) ? vals[3] : 0.f;
      ((float4*)(gdense + (size_t)b * Md))[t] = g;
    }
    __syncthreads();  // C2: publish sidx/sval/scnt for next iteration
  }

  // ---- epilogue: norms[49] term for final Gamma (same math as R3 k_norm50) --
  const int cnt = scnt;
  if (wv == 0) {
    double part = 0.0;
    if (lane < cnt) {
      const int id = sidx[lane];
      float acc2 = 0.f;
      for (int k = 0; k < cnt; ++k)
        acc2 = fmaf(sval[k], Q[(size_t)sidx[k] * Md + id], acc2);
      part = (double)sval[lane] * ((double)acc2 - 2.0 * (double)yws[id]);
    }
    part = wave_reduce_d(part);
    if (lane == 0) atomicAdd(&normacc[IHT - 1], part);
  }
}

__global__ void k_wnorms(const double* __restrict__ dacc, float* __restrict__ onorms) {
  const int t = threadIdx.x;
  if (t < IHT) {
    const double yn2 = dacc[0];
    double r2 = yn2 + dacc[1 + t];
    if (r2 < 0.0) r2 = 0.0;
    onorms[t] = (float)(sqrt(r2) / sqrt(yn2));
  }
}

extern "C" void kernel_launch(void* const* d_in, const int* in_sizes, int n_in,
                              void* d_out, int out_size, void* d_ws, size_t ws_size,
                              hipStream_t stream) {
  (void)in_sizes; (void)n_in; (void)out_size; (void)ws_size;  // K hardcoded = 64
  const float* Y = (const float*)d_in[0];  // [1024,512]
  const float* W = (const float*)d_in[1];  // [512,1024]
  float* out = (float*)d_out;
  float* outX = out;                   // [512,1024]
  float* outG = out + Nd * Md;         // [1024,1024]
  float* outN = outG + Bd * Md;        // [50]

  // workspace layout (~11.5 MB)
  char* wsb = (char*)d_ws;
  double* dacc = (double*)wsb;               // 51 doubles
  float* cbuf = (float*)(wsb + 512);         // [0]=c, [1]=eta
  float* Wn = (float*)(wsb + 1024);          // 512*1024
  float* Q = Wn + Nd * Md;                   // 1024*1024
  float* YW = Q + Md * Md;                   // 1024*1024
  float* Smat = YW + Bd * Md;                // 512*512
  float* S2 = Smat + Nd * Nd;                // 512*512
  float* cnorm = S2 + Nd * Nd;               // 1024
  float* X0 = cnorm + Md;                    // 1024
  float* V = X0 + Md;                        // 4*512 power-iter slots

  k_zero<<<1, 64, 0, stream>>>(dacc);
  k_colnorm<<<4, 256, 0, stream>>>(W, cnorm);
  k_normalize<<<2048, 256, 0, stream>>>(W, cnorm, Wn);

  // S = Wn Wn^T (512x512, K=1024); S2 = S*S/64; Q = Wn^T Wn (K=512); YW = Y Wn
  k_gemm_t<64, 32, 2><<<dim3(16, 8), 256, 0, stream>>>(Wn, Md, 0, Wn, Md, 1, Smat, Nd, Md, 1.0f);
  k_gemm_t<64, 32, 2><<<dim3(16, 8), 256, 0, stream>>>(Smat, Nd, 0, Smat, Nd, 0, S2, Nd, Nd, 0.015625f);
  k_gemm_t<64, 64, 4><<<dim3(16, 16), 256, 0, stream>>>(Wn, Md, 1, Wn, Md, 0, Q, Md, Nd, 1.0f);
  k_gemm_t<64, 64, 4><<<dim3(16, 16), 256, 0, stream>>>(Y, Nd, 0, Wn, Md, 0, YW, Md, Nd, 1.0f);
  k_yn2<<<128, 256, 0, stream>>>(Y, dacc);

  // power method in Z-space: z0 = X0 @ Wn^T; 49 steps of S2, 2 steps of S/8
  // (untouched — eta must stay bit-identical)
  k_x0<<<1, 512, 0, stream>>>(X0);
  k_z0<<<128, 256, 0, stream>>>(X0, Wn, V);
  float* pin = V;
  float* pout = V + 512;
  for (int i = 0; i < 49; ++i) {
    k_pmv<<<128, 256, 0, stream>>>(S2, pin, pout, 1.0f);
    float* tp = pin; pin = pout; pout = tp;
  }
  k_pmv<<<128, 256, 0, stream>>>(Smat, pin, V + 1024, 0.125f);        // v99
  k_pmv<<<128, 256, 0, stream>>>(Smat, V + 1024, V + 1536, 0.125f);   // v100
  k_pfinal<<<1, 512, 0, stream>>>(V + 1024, V + 1536, cbuf);

  // IHT: init + 50 iterations + final norm term, all in ONE launch
  k_iht_all<<<1024, 256, 0, stream>>>(Q, YW, cbuf, outG, dacc + 1);
  k_wnorms<<<1, 64, 0, stream>>>(dacc, outN);

  // X = Wn @ Gamma (512x1024, K=1024) reading dense Gamma from d_out
  k_gemm_t<64, 32, 2><<<dim3(32, 8), 256, 0, stream>>>(Wn, Md, 0, outG, Md, 0, outX, Md, Md, 1.0f);
}